// Round 15
// baseline (227.261 us; speedup 1.0000x reference)
//
#include <hip/hip_runtime.h>
#include <math.h>

// Problem constants: B=8, C=64, H=W=192, HW=36864, MODES=32, NB=4, BS=16, E=16
#define TPI 6.283185307179586f

typedef __attribute__((ext_vector_type(8))) short bf8v;   // 8 bf16 (4 VGPRs)
typedef __attribute__((ext_vector_type(4))) float f4v;    // 4 fp32 acc

#define MFMA(a,b,c) __builtin_amdgcn_mfma_f32_16x16x32_bf16((a),(b),(c),0,0,0)

__device__ __forceinline__ float gelu_f(float v){          // exact (erf)
  return 0.5f*v*(1.0f+erff(v*0.7071067811865475f));
}
// tanh-form gelu via fast exp + fast rcp (no IEEE div): err ~5e-4 abs
__device__ __forceinline__ float gelu_fast(float x){
  float x2=x*x;
  float inner=fmaf(0.044715f*x2, x, x);
  float e=__expf(1.5957691216057308f*inner);   // exp(2*0.7978845608*inner)
  float r=__builtin_amdgcn_rcpf(1.0f+e);
  return fmaf(-x, r, x);                        // x*(1-r)
}
// sigmoid-form gelu: x*sigmoid(1.702x). err <= ~0.0203 abs
__device__ __forceinline__ float gelu_sig(float x){
  float e=__expf(-1.702f*x);
  return x*__builtin_amdgcn_rcpf(1.0f+e);
}
__device__ __forceinline__ unsigned short f2b(float f){   // f32 -> bf16 (RNE)
  union{float f; unsigned u;} v; v.f=f;
  unsigned r=v.u + 0x7FFFu + ((v.u>>16)&1u);
  return (unsigned short)(r>>16);
}
__device__ __forceinline__ float b2f(unsigned short h){
  union{unsigned u; float f;} v; v.u=((unsigned)h)<<16; return v.f;
}

// ---------------- prep: twiddle tables + bf16 weights + zero gfp -----------
__global__ __launch_bounds__(256) void prep(const float* __restrict__ shw, const float* __restrict__ exw,
    const float* __restrict__ shb, const float* __restrict__ exb, const float* __restrict__ few,
    unsigned short* __restrict__ T, unsigned short* __restrict__ wall, float* __restrict__ ball,
    unsigned short* __restrict__ wfe, float* __restrict__ gfp){
  const float a = TPI/192.0f;
  int stride=gridDim.x*256;
  for(int i=blockIdx.x*256+threadIdx.x; i<61440; i+=stride){
    float v;
    if(i<12288){
      int n1=i/192, w=i%192; int kw=n1>>1, c=n1&1;
      int m=(kw*w)%192; float cs,sn; sincosf((float)m*a,&sn,&cs);
      v = c ? -sn : cs;
    } else if(i<36864){
      int j=i-12288; int n1=j/384, k1=j%384; int kh=n1>>1, d=n1&1; int h=k1>>1, c=k1&1;
      int m=(kh*h)%192; float cs,sn; sincosf((float)m*a,&sn,&cs);
      float e = d ? (c ? cs : -sn) : (c ? sn : cs);
      v = e*(1.0f/192.0f);
    } else if(i<49152){
      int j=i-36864; int h=j/64, k1=j%64; int kh=k1>>1, c=k1&1;
      int m=(h*kh)%192; float cs,sn; sincosf((float)m*a,&sn,&cs);
      v = c ? sn : cs;
    } else {
      int j=i-49152; int w=j/64, k1=j%64; int kw=k1>>1, d=k1&1;
      float f = kw ? (2.0f/192.0f) : (1.0f/192.0f);
      int m=(w*kw)%192; float cs,sn; sincosf((float)m*a,&sn,&cs);
      v = d ? -f*sn : f*cs;
    }
    T[i]=f2b(v);
  }
  for(int i=blockIdx.x*256+threadIdx.x;i<73728;i+=stride) wall[i]=f2b(i<8192?shw[i]:exw[i-8192]);
  for(int i=blockIdx.x*256+threadIdx.x;i<1152;i+=stride)  ball[i]=(i<128)?shb[i]:exb[i-128];
  for(int i=blockIdx.x*256+threadIdx.x;i<4096;i+=stride)  wfe[i]=f2b(few[i]);
  for(int i=blockIdx.x*256+threadIdx.x;i<512;i+=stride)   gfp[i]=0.f;
}

__global__ void gn_finalize(const float* __restrict__ part, const float* __restrict__ gw,
                            const float* __restrict__ gb, float2* __restrict__ sb){
  int g=threadIdx.x; if(g>=64) return;
  float S=0,SS=0;
  for(int j=0;j<8;j++){ S+=part[(g*8+j)*2]; SS+=part[(g*8+j)*2+1]; }
  const float inv=1.0f/294912.0f;
  float mean=S*inv, var=SS*inv-mean*mean;
  float rstd=rsqrtf(var+1e-5f);
  int b=g>>3, gg=g&7;
  for(int k=0;k<8;k++){
    int c=gg*8+k;
    float sc=rstd*gw[c];
    sb[b*64+c]=make_float2(sc, gb[c]-mean*sc);
  }
}

// ---------------- fwd DFT on RAW x (gn1 folded out via linearity) ---------
__global__ __launch_bounds__(256) void fwd_dft(const float* __restrict__ x,
      const unsigned short* __restrict__ TBf1, const unsigned short* __restrict__ TBf2,
      float* __restrict__ Xm2, float* __restrict__ part1){
  __shared__ __align__(16) unsigned short ldsA[64*200];  // Bt1 [64][200]; later tL [32][392]
  __shared__ __align__(16) float sX[2048];
  __shared__ float red[8];
  int t=threadIdx.x, bc=blockIdx.x;
  int wave=t>>6, l=t&63, lr=l&15, lg=l>>4;
  const float* xch = x + (size_t)bc*36864;
  for(int i=t;i<1536;i+=256){
    int row=i/24, chunk=i%24;
    *(uint4*)&ldsA[row*200 + chunk*8] = *(const uint4*)(TBf1 + row*192 + chunk*8);
  }
  __syncthreads();
  float s_=0.f, ss_=0.f;
  // ---- stage 1 ----
  f4v acc1[3][4];
  for(int mt=0;mt<3;mt++){
    int m0=(wave+mt*4)*16;
    const float* xrow = xch + (m0+lr)*192 + lg*8;
    bf8v af[6];
    #pragma unroll
    for(int ks=0;ks<6;ks++){
      float4 u0=*(const float4*)(xrow+ks*32);
      float4 u1=*(const float4*)(xrow+ks*32+4);
      s_ += u0.x+u0.y+u0.z+u0.w+u1.x+u1.y+u1.z+u1.w;
      ss_+= u0.x*u0.x+u0.y*u0.y+u0.z*u0.z+u0.w*u0.w
           +u1.x*u1.x+u1.y*u1.y+u1.z*u1.z+u1.w*u1.w;
      bf8v a;
      a[0]=(short)f2b(u0.x); a[1]=(short)f2b(u0.y); a[2]=(short)f2b(u0.z); a[3]=(short)f2b(u0.w);
      a[4]=(short)f2b(u1.x); a[5]=(short)f2b(u1.y); a[6]=(short)f2b(u1.z); a[7]=(short)f2b(u1.w);
      af[ks]=a;
    }
    #pragma unroll
    for(int nt=0;nt<4;nt++){
      f4v acc={0.f,0.f,0.f,0.f};
      #pragma unroll
      for(int ks=0;ks<6;ks++){
        bf8v b=*(const bf8v*)&ldsA[(nt*16+lr)*200 + ks*32 + lg*8];
        acc=MFMA(af[ks],b,acc);
      }
      acc1[mt][nt]=acc;
    }
  }
  __syncthreads();            // reuse ldsA as tL [32][392]
  for(int mt=0;mt<3;mt++){
    int m0=(wave+mt*4)*16;
    #pragma unroll
    for(int nt=0;nt<4;nt++){
      int n1=nt*16+lr; int kw=n1>>1, c=n1&1;
      #pragma unroll
      for(int reg=0;reg<4;reg++){
        int h=m0+4*lg+reg;
        ldsA[kw*392 + 2*h + c]=f2b(acc1[mt][nt][reg]);
      }
    }
  }
  __syncthreads();
  // ---- stage 2 ----
  for(int pp=0;pp<2;pp++){
    int p=wave+pp*4;
    int m0=(p>>2)*16, n0=(p&3)*16;
    f4v acc={0.f,0.f,0.f,0.f};
    #pragma unroll
    for(int ks=0;ks<12;ks++){
      bf8v a=*(const bf8v*)&ldsA[(m0+lr)*392 + ks*32 + lg*8];
      bf8v b=*(const bf8v*)(TBf2 + (n0+lr)*384 + ks*32 + lg*8);
      acc=MFMA(a,b,acc);
    }
    int n1=n0+lr; int kh=n1>>1, d=n1&1;
    #pragma unroll
    for(int reg=0;reg<4;reg++){
      int kw=m0+4*lg+reg;
      sX[(kh*32+kw)*2 + d]=acc[reg];
    }
  }
  __syncthreads();
  float* dst=Xm2+(size_t)bc*2048;
  for(int i=t;i<512;i+=256) *(float4*)(dst+i*4)=*(const float4*)(sX+i*4);
  // ---- gn1 stats ----
  #pragma unroll
  for(int o=32;o>0;o>>=1){ s_+=__shfl_down(s_,o); ss_+=__shfl_down(ss_,o); }
  if(l==0){ red[wave]=s_; red[4+wave]=ss_; }
  __syncthreads();
  if(t==0){
    part1[bc*2]  =red[0]+red[1]+red[2]+red[3];
    part1[bc*2+1]=red[4]+red[5]+red[6]+red[7];
  }
}

// ---------------- block-diagonal complex 2-layer MLP on modes -------------
__global__ __launch_bounds__(256) void mode_mlp(const float* __restrict__ Xm2, const float2* __restrict__ sb1,
    const float* __restrict__ w1, const float* __restrict__ b1,
    const float* __restrict__ w2, const float* __restrict__ b2,
    float* __restrict__ S2){
  __shared__ float w10[1024], w11[1024], w20[1024], w21[1024];
  __shared__ float b10[64], b11[64], b20[64], b21[64];
  __shared__ float2 sbl[64];
  __shared__ float xr[32][64], xi[32][64];
  __shared__ float o1r[32][64], o1i[32][64];
  int t=threadIdx.x;
  int b=blockIdx.x>>5, kh=blockIdx.x&31;
  for(int i=t;i<1024;i+=256){ w10[i]=w1[i]; w11[i]=w1[1024+i]; w20[i]=w2[i]; w21[i]=w2[1024+i]; }
  if(t<64){ b10[t]=b1[t]; b11[t]=b1[64+t]; b20[t]=b2[t]; b21[t]=b2[64+t]; sbl[t]=sb1[b*64+t]; }
  __syncthreads();
  for(int q=0;q<16;q++){
    int idx=q*256+t; int c=idx>>6, jj=idx&63;
    float2 s=sbl[c];
    float v=Xm2[((size_t)(b*64+c))*2048 + kh*64 + jj]*s.x;
    if(kh==0 && jj==0) v += 192.0f*s.y;
    if(jj&1) xi[jj>>1][c]=v; else xr[jj>>1][c]=v;
  }
  __syncthreads();
  int tl=t&63, n=tl>>4, o=tl&15, wb=n*256+o;
  #pragma unroll
  for(int it=0;it<8;it++){
    int kw=(t>>6)+it*4;
    float a_r=b10[tl], a_i=b11[tl];
    #pragma unroll
    for(int i=0;i<16;i++){
      float rr=xr[kw][n*16+i], im=xi[kw][n*16+i];
      float W0=w10[wb+i*16], W1=w11[wb+i*16];
      a_r=fmaf(rr,W0,fmaf(-im,W1,a_r));
      a_i=fmaf(im,W0,fmaf( rr,W1,a_i));
    }
    o1r[kw][tl]=gelu_f(a_r); o1i[kw][tl]=gelu_f(a_i);
  }
  __syncthreads();
  #pragma unroll
  for(int it=0;it<8;it++){
    int kw=(t>>6)+it*4;
    float c_r=b20[tl], c_i=b21[tl];
    #pragma unroll
    for(int i=0;i<16;i++){
      float rr=o1r[kw][n*16+i], im=o1i[kw][n*16+i];
      float W0=w20[wb+i*16], W1=w21[wb+i*16];
      c_r=fmaf(rr,W0,fmaf(-im,W1,c_r));
      c_i=fmaf(im,W0,fmaf( rr,W1,c_i));
    }
    xr[kw][tl]=c_r; xi[kw][tl]=c_i;
  }
  __syncthreads();
  for(int q=0;q<16;q++){
    int idx=q*256+t; int c=idx>>6, jj=idx&63;
    float v = (jj&1) ? xi[jj>>1][c] : xr[jj>>1][c];
    S2[((size_t)(b*64+c))*2048 + kh*64 + jj]=v;
  }
}

// ---------------- inverse DFT + residuals + gn2 stats (h2 -> bf16) --------
__global__ __launch_bounds__(256) void inv_dft(const float* __restrict__ S2,
      const unsigned short* __restrict__ TAi, const unsigned short* __restrict__ TBi,
      const float* __restrict__ x, const float2* __restrict__ sb,
      unsigned short* __restrict__ h2b, float* __restrict__ part2){
  __shared__ __align__(16) unsigned short Bs[64*72];
  __shared__ __align__(16) unsigned short GL[192*72];
  __shared__ float red[8];
  int t=threadIdx.x, bc=blockIdx.x;
  int wave=t>>6, l=t&63, lr=l&15, lg=l>>4;
  const float* sp=S2+(size_t)bc*2048;
  for(int i=t;i<1024;i+=256){
    int kh=i>>5, kw=i&31;
    float Sr=sp[(kh*32+kw)*2], Si=sp[(kh*32+kw)*2+1];
    unsigned short br=f2b(Sr), bi_=f2b(Si), nbi=f2b(-Si);
    Bs[(2*kw+0)*72 + 2*kh+0]=br;
    Bs[(2*kw+0)*72 + 2*kh+1]=nbi;
    Bs[(2*kw+1)*72 + 2*kh+0]=bi_;
    Bs[(2*kw+1)*72 + 2*kh+1]=br;
  }
  __syncthreads();
  for(int mt=0;mt<3;mt++){
    int m0=(wave+mt*4)*16;
    bf8v a0=*(const bf8v*)(TAi + (m0+lr)*64 + lg*8);
    bf8v a1=*(const bf8v*)(TAi + (m0+lr)*64 + 32 + lg*8);
    #pragma unroll
    for(int nt=0;nt<4;nt++){
      f4v acc={0.f,0.f,0.f,0.f};
      bf8v b0=*(const bf8v*)&Bs[(nt*16+lr)*72 + lg*8];
      bf8v b1=*(const bf8v*)&Bs[(nt*16+lr)*72 + 32 + lg*8];
      acc=MFMA(a0,b0,acc); acc=MFMA(a1,b1,acc);
      #pragma unroll
      for(int reg=0;reg<4;reg++)
        GL[(m0+4*lg+reg)*72 + nt*16+lr]=f2b(acc[reg]);
    }
  }
  __syncthreads();
  float2 sv=sb[bc];
  float cA=sv.x+1.0f, cB=sv.y;
  asm volatile("" : "+v"(cA), "+v"(cB));   // pin to VGPR (constant-bus fix)
  const float* xch=x+(size_t)bc*36864;
  unsigned short* och=h2b+(size_t)bc*36864;
  float s_=0.f, ss_=0.f;
  for(int mt=0;mt<3;mt++){
    int m0=(wave+mt*4)*16;
    bf8v a0=*(const bf8v*)&GL[(m0+lr)*72 + lg*8];
    bf8v a1=*(const bf8v*)&GL[(m0+lr)*72 + 32 + lg*8];
    for(int nt=0;nt<12;nt++){
      int n0=nt*16;
      f4v acc={0.f,0.f,0.f,0.f};
      bf8v b0=*(const bf8v*)(TBi + (n0+lr)*64 + lg*8);
      bf8v b1=*(const bf8v*)(TBi + (n0+lr)*64 + 32 + lg*8);
      acc=MFMA(a0,b0,acc); acc=MFMA(a1,b1,acc);
      int w=n0+lr;
      #pragma unroll
      for(int reg=0;reg<4;reg++){
        int h=m0+4*lg+reg;
        int ga=h*192+w;
        float xv=xch[ga];
        float val=acc[reg]+fmaf(cA,xv,cB);
        och[ga]=f2b(val);
        s_+=val; ss_+=val*val;
      }
    }
  }
  #pragma unroll
  for(int o=32;o>0;o>>=1){ s_+=__shfl_down(s_,o); ss_+=__shfl_down(ss_,o); }
  if(l==0){ red[wave]=s_; red[4+wave]=ss_; }
  __syncthreads();
  if(t==0){
    part2[bc*2]  =red[0]+red[1]+red[2]+red[3];
    part2[bc*2+1]=red[4]+red[5]+red[6]+red[7];
  }
}

// ---------------- gf_k: gating means + feats materialization (bf16 in) ----
__global__ __launch_bounds__(256,4) void gf_k(const unsigned short* __restrict__ h2b, const float2* __restrict__ sb,
    const unsigned short* __restrict__ wfe, const float* __restrict__ feb,
    float* __restrict__ gfp, unsigned short* __restrict__ feats){
  __shared__ __align__(16) unsigned short A[128*72];
  __shared__ float sgf[64];
  int t=threadIdx.x;
  int blk=blockIdx.x, b=blk/288, tile=blk-b*288, hw0=tile*128;
  if(t<64) sgf[t]=0.f;
  // batched staging loads (4 outstanding uint4 = 8 bf16 each)
  uint4 v[4];
  #pragma unroll
  for(int k=0;k<4;k++){
    int i=t+k*256; int c=i>>4, o=i&15;
    v[k]=*(const uint4*)&h2b[(size_t)(b*64+c)*36864 + hw0 + o*8];
  }
  #pragma unroll
  for(int k=0;k<4;k++){
    int i=t+k*256; int c=i>>4, o=i&15;
    float2 s=sb[b*64+c];
    int sw=((o>>1)&3)<<3, cc=c^sw;
    const unsigned short* pv=(const unsigned short*)&v[k];
    #pragma unroll
    for(int r=0;r<8;r++)
      A[(o*8+r)*72+cc]=f2b(fmaf(b2f(pv[r]),s.x,s.y));
  }
  __syncthreads();
  int wave=t>>6, l=t&63, lr=l&15, lg=l>>4;
  int pxb=wave*32;
  bf8v af[2][2];
  #pragma unroll
  for(int fm=0;fm<2;fm++){
    int row=pxb+fm*16+lr, sw=((row>>4)&3)<<3;
    #pragma unroll
    for(int ks=0;ks<2;ks++) af[fm][ks]=*(const bf8v*)&A[row*72+((ks*32+lg*8)^sw)];
  }
  float gsum[4]={0.f,0.f,0.f,0.f};
  #pragma unroll
  for(int fn=0;fn<4;fn++){
    bf8v b0=*(const bf8v*)(wfe+(fn*16+lr)*64+lg*8);
    bf8v b1=*(const bf8v*)(wfe+(fn*16+lr)*64+32+lg*8);
    float bs=feb[fn*16+lr];
    #pragma unroll
    for(int fm=0;fm<2;fm++){
      f4v acc={0.f,0.f,0.f,0.f};
      acc=MFMA(af[fm][0],b0,acc);
      acc=MFMA(af[fm][1],b1,acc);
      int swm=(((pxb+fm*16)>>4)&3)<<3;
      int cc=(fn*16+lr)^swm;
      #pragma unroll
      for(int r=0;r<4;r++){
        float g=gelu_fast(acc[r]+bs);
        gsum[fn]+=g;
        A[(pxb+fm*16+4*lg+r)*72+cc]=f2b(g);   // wave-private rows
      }
    }
  }
  #pragma unroll
  for(int fn=0;fn<4;fn++){
    float v2=gsum[fn];
    v2+=__shfl_xor(v2,16); v2+=__shfl_xor(v2,32);
    if(lg==0) atomicAdd(&sgf[fn*16+lr], v2);
  }
  __syncthreads();
  if(t<64) atomicAdd(&gfp[b*64+t], sgf[t]);
  // store feats tile bf16 (coalesced: 128B contiguous per 8 threads)
  #pragma unroll
  for(int k=0;k<4;k++){
    int i=t+k*256; int px=i>>3, c0=(i&7)*8, sw=((px>>4)&3)<<3;
    *(uint4*)&feats[(size_t)(b*36864+hw0+px)*64+c0] = *(const uint4*)&A[px*72+(c0^sw)];
  }
}

// ---------------- gating MLP + top-4 softmax -> active-term list ----------
__global__ __launch_bounds__(128) void gating(const float* __restrict__ gfp,
  const float* __restrict__ g1w, const float* __restrict__ g1b,
  const float* __restrict__ bn1g, const float* __restrict__ bn1b, const float* __restrict__ bn1m, const float* __restrict__ bn1v,
  const float* __restrict__ cw1, const float* __restrict__ cb1, const float* __restrict__ cw2, const float* __restrict__ cb2,
  const float* __restrict__ g2w, const float* __restrict__ g2b,
  const float* __restrict__ bn2g, const float* __restrict__ bn2b, const float* __restrict__ bn2m, const float* __restrict__ bn2v,
  const float* __restrict__ g3w, const float* __restrict__ g3b, float2* __restrict__ act){
  __shared__ float gf[8][64];
  __shared__ float h1[8][128];
  __shared__ float a1[8][8];
  __shared__ float h2g[8][64];
  __shared__ float sc[8][16];
  int t=threadIdx.x;
  for(int i=t;i<512;i+=128) gf[i>>6][i&63]=gfp[i]*(1.0f/36864.0f);
  __syncthreads();
  for(int i=t;i<1024;i+=128){
    int b=i>>7, j=i&127;
    float s=g1b[j];
    for(int c=0;c<64;c++) s=fmaf(gf[b][c], g1w[j*64+c], s);
    s=(s-bn1m[j])*rsqrtf(bn1v[j]+1e-5f)*bn1g[j]+bn1b[j];
    h1[b][j]=gelu_f(s);
  }
  __syncthreads();
  if(t<64){
    int b=t>>3, k=t&7; float s=cb1[k];
    for(int j=0;j<128;j++) s=fmaf(h1[b][j], cw1[k*128+j], s);
    a1[b][k]=gelu_f(s);
  }
  __syncthreads();
  for(int i=t;i<1024;i+=128){
    int b=i>>7, j=i&127;
    float s=cb2[j];
    for(int k=0;k<8;k++) s=fmaf(a1[b][k], cw2[j*8+k], s);
    h1[b][j]=h1[b][j]/(1.0f+expf(-2.0f*s));
  }
  __syncthreads();
  for(int i=t;i<512;i+=128){
    int b=i>>6, j=i&63;
    float s=g2b[j];
    for(int k=0;k<128;k++) s=fmaf(h1[b][k], g2w[j*128+k], s);
    s=(s-bn2m[j])*rsqrtf(bn2v[j]+1e-5f)*bn2g[j]+bn2b[j];
    h2g[b][j]=gelu_f(s);
  }
  __syncthreads();
  {
    int b=t>>4, e=t&15;
    float s=g3b[e];
    for(int c=0;c<64;c++) s=fmaf(h2g[b][c], g3w[e*64+c], s);
    sc[b][e]=s;
  }
  __syncthreads();
  if(t<8){
    int b=t;
    float v[16];
    for(int e=0;e<16;e++) v[e]=sc[b][e];
    float vals[4]; int idx[4];
    for(int k=0;k<4;k++){
      float best=-1e30f; int bi=0;
      for(int e=0;e<16;e++) if(v[e]>best){best=v[e];bi=e;}
      vals[k]=best; idx[k]=bi; v[bi]=-1e30f;
    }
    float m=vals[0], ssum=0.f, w[4];
    for(int k=0;k<4;k++){ w[k]=expf((vals[k]-m)*0.5f); ssum+=w[k]; }
    act[b*6+0]=make_float2(0.5f, __int_as_float(0));
    act[b*6+1]=make_float2(0.5f, __int_as_float(1));
    for(int k=0;k<4;k++) act[b*6+2+k]=make_float2(w[k]/ssum, __int_as_float(2+idx[k]));
  }
}

// ---------------- experts: barrier-free, LDS-free -------------------------
// Direct-fragment feats loads; per-thread direct stores (a wave's 8 float4
// stores per oc cover one aligned 128B line). Residual from bf16 h2b
// (different buffer -> pure stores). Zero __syncthreads, zero LDS.
__global__ __launch_bounds__(256,4) void final_k(const unsigned short* __restrict__ feats,
  const unsigned short* __restrict__ h2b,
  const unsigned short* __restrict__ wall, const float* __restrict__ ball,
  const float2* __restrict__ act, float* __restrict__ out){
  int t=threadIdx.x;
  int blk=blockIdx.x, b=blk/288, tile=blk-b*288, hw0=tile*128;
  int wave=t>>6, l=t&63, lr=l&15, lg=l>>4;
  int pxb=wave*32;
  // preload active-term list (uniform per b)
  float gv[6]; int tv[6];
  #pragma unroll
  for(int j=0;j<6;j++){
    float2 aw=act[b*6+j];
    gv[j]=aw.x; tv[j]=__float_as_int(aw.y);
  }
  const unsigned short* fbase = feats + (size_t)(b*36864+hw0)*64;
  bf8v af2[2][2];
  #pragma unroll
  for(int fm=0;fm<2;fm++){
    int row=pxb+fm*16+lr;
    #pragma unroll
    for(int ks=0;ks<2;ks++)
      af2[fm][ks]=*(const bf8v*)(fbase + (size_t)row*64 + ks*32 + lg*8);
  }
  #pragma unroll
  for(int half=0;half<2;half++){
    float oa[2][2][4]={};       // [fm][fn2][r]
    #pragma unroll
    for(int j=0;j<6;j++){
      float g=gv[j];
      const unsigned short* wp=wall+tv[j]*4096;
      const float* bp=ball+tv[j]*64;
      #pragma unroll
      for(int fn2=0;fn2<2;fn2++){
        int fn=half*2+fn2;
        bf8v b0=*(const bf8v*)(wp+(fn*16+lr)*64+lg*8);
        bf8v b1=*(const bf8v*)(wp+(fn*16+lr)*64+32+lg*8);
        float bs=bp[fn*16+lr];
        #pragma unroll
        for(int fm=0;fm<2;fm++){
          f4v acc={0.f,0.f,0.f,0.f};
          acc=MFMA(af2[fm][0],b0,acc);
          acc=MFMA(af2[fm][1],b1,acc);
          #pragma unroll
          for(int r=0;r<4;r++)
            oa[fm][fn2][r]=fmaf(g, gelu_sig(acc[r]+bs), oa[fm][fn2][r]);
        }
      }
    }
    // direct store: out = expert + bf16 residual; per-wave stores complete
    // each 128B line (lg x fm cover px pxb..pxb+31 per oc)
    #pragma unroll
    for(int fm=0;fm<2;fm++)
      #pragma unroll
      for(int fn2=0;fn2<2;fn2++){
        int oc=half*32+fn2*16+lr;
        int px=pxb+fm*16+4*lg;
        size_t base=(size_t)(b*64+oc)*36864 + hw0 + px;
        ushort4 hv=*(const ushort4*)&h2b[base];
        float4 o=make_float4(oa[fm][fn2][0]+b2f(hv.x),
                             oa[fm][fn2][1]+b2f(hv.y),
                             oa[fm][fn2][2]+b2f(hv.z),
                             oa[fm][fn2][3]+b2f(hv.w));
        *(float4*)&out[base]=o;
      }
  }
}

extern "C" void kernel_launch(void* const* d_in, const int* in_sizes, int n_in,
                              void* d_out, int out_size, void* d_ws, size_t ws_size,
                              hipStream_t stream){
  const float* x    =(const float*)d_in[0];
  const float* gn1w =(const float*)d_in[1];
  const float* gn1b =(const float*)d_in[2];
  const float* aw1  =(const float*)d_in[3];
  const float* ab1  =(const float*)d_in[4];
  const float* aw2  =(const float*)d_in[5];
  const float* ab2  =(const float*)d_in[6];
  const float* gn2w =(const float*)d_in[7];
  const float* gn2b =(const float*)d_in[8];
  const float* few  =(const float*)d_in[9];
  const float* feb  =(const float*)d_in[10];
  const float* g1w  =(const float*)d_in[11];
  const float* g1b  =(const float*)d_in[12];
  const float* bn1g =(const float*)d_in[13];
  const float* bn1b =(const float*)d_in[14];
  const float* bn1m =(const float*)d_in[15];
  const float* bn1v =(const float*)d_in[16];
  const float* cw1  =(const float*)d_in[17];
  const float* cb1  =(const float*)d_in[18];
  const float* cw2  =(const float*)d_in[19];
  const float* cb2  =(const float*)d_in[20];
  const float* g2w  =(const float*)d_in[21];
  const float* g2b  =(const float*)d_in[22];
  const float* bn2g =(const float*)d_in[23];
  const float* bn2b =(const float*)d_in[24];
  const float* bn2m =(const float*)d_in[25];
  const float* bn2v =(const float*)d_in[26];
  const float* g3w  =(const float*)d_in[27];
  const float* g3b  =(const float*)d_in[28];
  const float* shw  =(const float*)d_in[29];
  const float* shb  =(const float*)d_in[30];
  const float* exw  =(const float*)d_in[31];
  const float* exb  =(const float*)d_in[32];

  float* out=(float*)d_out;
  float* ws=(float*)d_ws;

  // workspace layout (float offsets)
  float*  part1 = ws;                         // 1024
  float*  part2 = ws+1024;                    // 1024
  float2* sb1   = (float2*)(ws+2048);         // 512 float2
  float2* sb2   = (float2*)(ws+3072);         // 512 float2
  float2* act   = (float2*)(ws+4096);         // 48 float2
  float*  gfp   = ws+4224;                    // 512
  float*  Xm2   = ws+8192;                    // 1048576
  float*  S2    = ws+1056768;                 // 1048576
  unsigned short* Tbl  = (unsigned short*)(ws+2105344);  // 61440 shorts
  unsigned short* wall = (unsigned short*)(ws+2136064);  // 73728 shorts
  float*          ball = ws+2172928;                     // 1152
  unsigned short* wfe  = (unsigned short*)(ws+2174080);  // 4096 shorts
  unsigned short* feats= (unsigned short*)(ws+2176128);  // 18874368 shorts (~37.7MB)
  unsigned short* h2b  = (unsigned short*)(ws+11613312); // 18874368 shorts (~37.7MB)
  const unsigned short* TBf1 = Tbl;
  const unsigned short* TBf2 = Tbl+12288;
  const unsigned short* TAi  = Tbl+36864;
  const unsigned short* TBi  = Tbl+49152;

  prep<<<64,256,0,stream>>>(shw, exw, shb, exb, few, Tbl, wall, ball, wfe, gfp);
  // AFNO on raw x (gn1 via linearity), emits gn1 stats
  fwd_dft <<<512,256,0,stream>>>(x, TBf1, TBf2, Xm2, part1);
  gn_finalize<<<1,64,0,stream>>>(part1, gn1w, gn1b, sb1);
  mode_mlp<<<256,256,0,stream>>>(Xm2, sb1, aw1, ab1, aw2, ab2, S2);
  inv_dft <<<512,256,0,stream>>>(S2, TAi, TBi, x, sb1, h2b, part2); // h2 -> bf16 workspace
  gn_finalize<<<1,64,0,stream>>>(part2, gn2w, gn2b, sb2);
  // gating means + feats materialization (bf16 in/out)
  gf_k<<<2304,256,0,stream>>>(h2b, sb2, wfe, feb, gfp, feats);
  gating <<<1,128,0,stream>>>(gfp, g1w,g1b, bn1g,bn1b,bn1m,bn1v,
                              cw1,cb1,cw2,cb2, g2w,g2b, bn2g,bn2b,bn2m,bn2v,
                              g3w,g3b, act);
  // experts: barrier-free, LDS-free, pure stores
  final_k<<<2304,256,0,stream>>>(feats, h2b, wall, ball, act, out);
}

// Round 16
// 204.862 us; speedup vs baseline: 1.1093x; 1.1093x over previous
//
#include <hip/hip_runtime.h>
#include <math.h>

// Problem constants: B=8, C=64, H=W=192, HW=36864, MODES=32, NB=4, BS=16, E=16
#define TPI 6.283185307179586f

typedef __attribute__((ext_vector_type(8))) short bf8v;   // 8 bf16 (4 VGPRs)
typedef __attribute__((ext_vector_type(4))) float f4v;    // 4 fp32 acc

#define MFMA(a,b,c) __builtin_amdgcn_mfma_f32_16x16x32_bf16((a),(b),(c),0,0,0)

__device__ __forceinline__ float gelu_f(float v){          // exact (erf)
  return 0.5f*v*(1.0f+erff(v*0.7071067811865475f));
}
// tanh-form gelu via fast exp + fast rcp (no IEEE div): err ~5e-4 abs
__device__ __forceinline__ float gelu_fast(float x){
  float x2=x*x;
  float inner=fmaf(0.044715f*x2, x, x);
  float e=__expf(1.5957691216057308f*inner);   // exp(2*0.7978845608*inner)
  float r=__builtin_amdgcn_rcpf(1.0f+e);
  return fmaf(-x, r, x);                        // x*(1-r)
}
// sigmoid-form gelu: x*sigmoid(1.702x). err <= ~0.0203 abs
__device__ __forceinline__ float gelu_sig(float x){
  float e=__expf(-1.702f*x);
  return x*__builtin_amdgcn_rcpf(1.0f+e);
}
__device__ __forceinline__ unsigned short f2b(float f){   // f32 -> bf16 (RNE)
  union{float f; unsigned u;} v; v.f=f;
  unsigned r=v.u + 0x7FFFu + ((v.u>>16)&1u);
  return (unsigned short)(r>>16);
}
__device__ __forceinline__ float b2f(unsigned short h){
  union{unsigned u; float f;} v; v.u=((unsigned)h)<<16; return v.f;
}

// ---------------- prep: twiddle tables + bf16 weights + zero gfp -----------
__global__ __launch_bounds__(256) void prep(const float* __restrict__ shw, const float* __restrict__ exw,
    const float* __restrict__ shb, const float* __restrict__ exb, const float* __restrict__ few,
    unsigned short* __restrict__ T, unsigned short* __restrict__ wall, float* __restrict__ ball,
    unsigned short* __restrict__ wfe, float* __restrict__ gfp){
  const float a = TPI/192.0f;
  int stride=gridDim.x*256;
  for(int i=blockIdx.x*256+threadIdx.x; i<61440; i+=stride){
    float v;
    if(i<12288){
      int n1=i/192, w=i%192; int kw=n1>>1, c=n1&1;
      int m=(kw*w)%192; float cs,sn; sincosf((float)m*a,&sn,&cs);
      v = c ? -sn : cs;
    } else if(i<36864){
      int j=i-12288; int n1=j/384, k1=j%384; int kh=n1>>1, d=n1&1; int h=k1>>1, c=k1&1;
      int m=(kh*h)%192; float cs,sn; sincosf((float)m*a,&sn,&cs);
      float e = d ? (c ? cs : -sn) : (c ? sn : cs);
      v = e*(1.0f/192.0f);
    } else if(i<49152){
      int j=i-36864; int h=j/64, k1=j%64; int kh=k1>>1, c=k1&1;
      int m=(h*kh)%192; float cs,sn; sincosf((float)m*a,&sn,&cs);
      v = c ? sn : cs;
    } else {
      int j=i-49152; int w=j/64, k1=j%64; int kw=k1>>1, d=k1&1;
      float f = kw ? (2.0f/192.0f) : (1.0f/192.0f);
      int m=(w*kw)%192; float cs,sn; sincosf((float)m*a,&sn,&cs);
      v = d ? -f*sn : f*cs;
    }
    T[i]=f2b(v);
  }
  for(int i=blockIdx.x*256+threadIdx.x;i<73728;i+=stride) wall[i]=f2b(i<8192?shw[i]:exw[i-8192]);
  for(int i=blockIdx.x*256+threadIdx.x;i<1152;i+=stride)  ball[i]=(i<128)?shb[i]:exb[i-128];
  for(int i=blockIdx.x*256+threadIdx.x;i<4096;i+=stride)  wfe[i]=f2b(few[i]);
  for(int i=blockIdx.x*256+threadIdx.x;i<512;i+=stride)   gfp[i]=0.f;
}

__global__ void gn_finalize(const float* __restrict__ part, const float* __restrict__ gw,
                            const float* __restrict__ gb, float2* __restrict__ sb){
  int g=threadIdx.x; if(g>=64) return;
  float S=0,SS=0;
  for(int j=0;j<8;j++){ S+=part[(g*8+j)*2]; SS+=part[(g*8+j)*2+1]; }
  const float inv=1.0f/294912.0f;
  float mean=S*inv, var=SS*inv-mean*mean;
  float rstd=rsqrtf(var+1e-5f);
  int b=g>>3, gg=g&7;
  for(int k=0;k<8;k++){
    int c=gg*8+k;
    float sc=rstd*gw[c];
    sb[b*64+c]=make_float2(sc, gb[c]-mean*sc);
  }
}

// ---------------- fwd DFT on RAW x (gn1 folded out via linearity) ---------
__global__ __launch_bounds__(256) void fwd_dft(const float* __restrict__ x,
      const unsigned short* __restrict__ TBf1, const unsigned short* __restrict__ TBf2,
      float* __restrict__ Xm2, float* __restrict__ part1){
  __shared__ __align__(16) unsigned short ldsA[64*200];  // Bt1 [64][200]; later tL [32][392]
  __shared__ __align__(16) float sX[2048];
  __shared__ float red[8];
  int t=threadIdx.x, bc=blockIdx.x;
  int wave=t>>6, l=t&63, lr=l&15, lg=l>>4;
  const float* xch = x + (size_t)bc*36864;
  for(int i=t;i<1536;i+=256){
    int row=i/24, chunk=i%24;
    *(uint4*)&ldsA[row*200 + chunk*8] = *(const uint4*)(TBf1 + row*192 + chunk*8);
  }
  __syncthreads();
  float s_=0.f, ss_=0.f;
  // ---- stage 1 ----
  f4v acc1[3][4];
  for(int mt=0;mt<3;mt++){
    int m0=(wave+mt*4)*16;
    const float* xrow = xch + (m0+lr)*192 + lg*8;
    bf8v af[6];
    #pragma unroll
    for(int ks=0;ks<6;ks++){
      float4 u0=*(const float4*)(xrow+ks*32);
      float4 u1=*(const float4*)(xrow+ks*32+4);
      s_ += u0.x+u0.y+u0.z+u0.w+u1.x+u1.y+u1.z+u1.w;
      ss_+= u0.x*u0.x+u0.y*u0.y+u0.z*u0.z+u0.w*u0.w
           +u1.x*u1.x+u1.y*u1.y+u1.z*u1.z+u1.w*u1.w;
      bf8v a;
      a[0]=(short)f2b(u0.x); a[1]=(short)f2b(u0.y); a[2]=(short)f2b(u0.z); a[3]=(short)f2b(u0.w);
      a[4]=(short)f2b(u1.x); a[5]=(short)f2b(u1.y); a[6]=(short)f2b(u1.z); a[7]=(short)f2b(u1.w);
      af[ks]=a;
    }
    #pragma unroll
    for(int nt=0;nt<4;nt++){
      f4v acc={0.f,0.f,0.f,0.f};
      #pragma unroll
      for(int ks=0;ks<6;ks++){
        bf8v b=*(const bf8v*)&ldsA[(nt*16+lr)*200 + ks*32 + lg*8];
        acc=MFMA(af[ks],b,acc);
      }
      acc1[mt][nt]=acc;
    }
  }
  __syncthreads();            // reuse ldsA as tL [32][392]
  for(int mt=0;mt<3;mt++){
    int m0=(wave+mt*4)*16;
    #pragma unroll
    for(int nt=0;nt<4;nt++){
      int n1=nt*16+lr; int kw=n1>>1, c=n1&1;
      #pragma unroll
      for(int reg=0;reg<4;reg++){
        int h=m0+4*lg+reg;
        ldsA[kw*392 + 2*h + c]=f2b(acc1[mt][nt][reg]);
      }
    }
  }
  __syncthreads();
  // ---- stage 2 ----
  for(int pp=0;pp<2;pp++){
    int p=wave+pp*4;
    int m0=(p>>2)*16, n0=(p&3)*16;
    f4v acc={0.f,0.f,0.f,0.f};
    #pragma unroll
    for(int ks=0;ks<12;ks++){
      bf8v a=*(const bf8v*)&ldsA[(m0+lr)*392 + ks*32 + lg*8];
      bf8v b=*(const bf8v*)(TBf2 + (n0+lr)*384 + ks*32 + lg*8);
      acc=MFMA(a,b,acc);
    }
    int n1=n0+lr; int kh=n1>>1, d=n1&1;
    #pragma unroll
    for(int reg=0;reg<4;reg++){
      int kw=m0+4*lg+reg;
      sX[(kh*32+kw)*2 + d]=acc[reg];
    }
  }
  __syncthreads();
  float* dst=Xm2+(size_t)bc*2048;
  for(int i=t;i<512;i+=256) *(float4*)(dst+i*4)=*(const float4*)(sX+i*4);
  // ---- gn1 stats ----
  #pragma unroll
  for(int o=32;o>0;o>>=1){ s_+=__shfl_down(s_,o); ss_+=__shfl_down(ss_,o); }
  if(l==0){ red[wave]=s_; red[4+wave]=ss_; }
  __syncthreads();
  if(t==0){
    part1[bc*2]  =red[0]+red[1]+red[2]+red[3];
    part1[bc*2+1]=red[4]+red[5]+red[6]+red[7];
  }
}

// ---------------- block-diagonal complex 2-layer MLP on modes -------------
__global__ __launch_bounds__(256) void mode_mlp(const float* __restrict__ Xm2, const float2* __restrict__ sb1,
    const float* __restrict__ w1, const float* __restrict__ b1,
    const float* __restrict__ w2, const float* __restrict__ b2,
    float* __restrict__ S2){
  __shared__ float w10[1024], w11[1024], w20[1024], w21[1024];
  __shared__ float b10[64], b11[64], b20[64], b21[64];
  __shared__ float2 sbl[64];
  __shared__ float xr[32][64], xi[32][64];
  __shared__ float o1r[32][64], o1i[32][64];
  int t=threadIdx.x;
  int b=blockIdx.x>>5, kh=blockIdx.x&31;
  for(int i=t;i<1024;i+=256){ w10[i]=w1[i]; w11[i]=w1[1024+i]; w20[i]=w2[i]; w21[i]=w2[1024+i]; }
  if(t<64){ b10[t]=b1[t]; b11[t]=b1[64+t]; b20[t]=b2[t]; b21[t]=b2[64+t]; sbl[t]=sb1[b*64+t]; }
  __syncthreads();
  for(int q=0;q<16;q++){
    int idx=q*256+t; int c=idx>>6, jj=idx&63;
    float2 s=sbl[c];
    float v=Xm2[((size_t)(b*64+c))*2048 + kh*64 + jj]*s.x;
    if(kh==0 && jj==0) v += 192.0f*s.y;
    if(jj&1) xi[jj>>1][c]=v; else xr[jj>>1][c]=v;
  }
  __syncthreads();
  int tl=t&63, n=tl>>4, o=tl&15, wb=n*256+o;
  #pragma unroll
  for(int it=0;it<8;it++){
    int kw=(t>>6)+it*4;
    float a_r=b10[tl], a_i=b11[tl];
    #pragma unroll
    for(int i=0;i<16;i++){
      float rr=xr[kw][n*16+i], im=xi[kw][n*16+i];
      float W0=w10[wb+i*16], W1=w11[wb+i*16];
      a_r=fmaf(rr,W0,fmaf(-im,W1,a_r));
      a_i=fmaf(im,W0,fmaf( rr,W1,a_i));
    }
    o1r[kw][tl]=gelu_f(a_r); o1i[kw][tl]=gelu_f(a_i);
  }
  __syncthreads();
  #pragma unroll
  for(int it=0;it<8;it++){
    int kw=(t>>6)+it*4;
    float c_r=b20[tl], c_i=b21[tl];
    #pragma unroll
    for(int i=0;i<16;i++){
      float rr=o1r[kw][n*16+i], im=o1i[kw][n*16+i];
      float W0=w20[wb+i*16], W1=w21[wb+i*16];
      c_r=fmaf(rr,W0,fmaf(-im,W1,c_r));
      c_i=fmaf(im,W0,fmaf( rr,W1,c_i));
    }
    xr[kw][tl]=c_r; xi[kw][tl]=c_i;
  }
  __syncthreads();
  for(int q=0;q<16;q++){
    int idx=q*256+t; int c=idx>>6, jj=idx&63;
    float v = (jj&1) ? xi[jj>>1][c] : xr[jj>>1][c];
    S2[((size_t)(b*64+c))*2048 + kh*64 + jj]=v;
  }
}

// ---------------- inverse DFT + residuals + gn2 stats (h2 -> bf16) --------
__global__ __launch_bounds__(256) void inv_dft(const float* __restrict__ S2,
      const unsigned short* __restrict__ TAi, const unsigned short* __restrict__ TBi,
      const float* __restrict__ x, const float2* __restrict__ sb,
      unsigned short* __restrict__ h2b, float* __restrict__ part2){
  __shared__ __align__(16) unsigned short Bs[64*72];
  __shared__ __align__(16) unsigned short GL[192*72];
  __shared__ float red[8];
  int t=threadIdx.x, bc=blockIdx.x;
  int wave=t>>6, l=t&63, lr=l&15, lg=l>>4;
  const float* sp=S2+(size_t)bc*2048;
  for(int i=t;i<1024;i+=256){
    int kh=i>>5, kw=i&31;
    float Sr=sp[(kh*32+kw)*2], Si=sp[(kh*32+kw)*2+1];
    unsigned short br=f2b(Sr), bi_=f2b(Si), nbi=f2b(-Si);
    Bs[(2*kw+0)*72 + 2*kh+0]=br;
    Bs[(2*kw+0)*72 + 2*kh+1]=nbi;
    Bs[(2*kw+1)*72 + 2*kh+0]=bi_;
    Bs[(2*kw+1)*72 + 2*kh+1]=br;
  }
  __syncthreads();
  for(int mt=0;mt<3;mt++){
    int m0=(wave+mt*4)*16;
    bf8v a0=*(const bf8v*)(TAi + (m0+lr)*64 + lg*8);
    bf8v a1=*(const bf8v*)(TAi + (m0+lr)*64 + 32 + lg*8);
    #pragma unroll
    for(int nt=0;nt<4;nt++){
      f4v acc={0.f,0.f,0.f,0.f};
      bf8v b0=*(const bf8v*)&Bs[(nt*16+lr)*72 + lg*8];
      bf8v b1=*(const bf8v*)&Bs[(nt*16+lr)*72 + 32 + lg*8];
      acc=MFMA(a0,b0,acc); acc=MFMA(a1,b1,acc);
      #pragma unroll
      for(int reg=0;reg<4;reg++)
        GL[(m0+4*lg+reg)*72 + nt*16+lr]=f2b(acc[reg]);
    }
  }
  __syncthreads();
  float2 sv=sb[bc];
  float cA=sv.x+1.0f, cB=sv.y;
  asm volatile("" : "+v"(cA), "+v"(cB));   // pin to VGPR (constant-bus fix)
  const float* xch=x+(size_t)bc*36864;
  unsigned short* och=h2b+(size_t)bc*36864;
  float s_=0.f, ss_=0.f;
  for(int mt=0;mt<3;mt++){
    int m0=(wave+mt*4)*16;
    bf8v a0=*(const bf8v*)&GL[(m0+lr)*72 + lg*8];
    bf8v a1=*(const bf8v*)&GL[(m0+lr)*72 + 32 + lg*8];
    for(int nt=0;nt<12;nt++){
      int n0=nt*16;
      f4v acc={0.f,0.f,0.f,0.f};
      bf8v b0=*(const bf8v*)(TBi + (n0+lr)*64 + lg*8);
      bf8v b1=*(const bf8v*)(TBi + (n0+lr)*64 + 32 + lg*8);
      acc=MFMA(a0,b0,acc); acc=MFMA(a1,b1,acc);
      int w=n0+lr;
      #pragma unroll
      for(int reg=0;reg<4;reg++){
        int h=m0+4*lg+reg;
        int ga=h*192+w;
        float xv=xch[ga];
        float val=acc[reg]+fmaf(cA,xv,cB);
        och[ga]=f2b(val);
        s_+=val; ss_+=val*val;
      }
    }
  }
  #pragma unroll
  for(int o=32;o>0;o>>=1){ s_+=__shfl_down(s_,o); ss_+=__shfl_down(ss_,o); }
  if(l==0){ red[wave]=s_; red[4+wave]=ss_; }
  __syncthreads();
  if(t==0){
    part2[bc*2]  =red[0]+red[1]+red[2]+red[3];
    part2[bc*2+1]=red[4]+red[5]+red[6]+red[7];
  }
}

// ---------------- gf_k: gating means + feats materialization (bf16 in) ----
__global__ __launch_bounds__(256,4) void gf_k(const unsigned short* __restrict__ h2b, const float2* __restrict__ sb,
    const unsigned short* __restrict__ wfe, const float* __restrict__ feb,
    float* __restrict__ gfp, unsigned short* __restrict__ feats){
  __shared__ __align__(16) unsigned short A[128*72];
  __shared__ float sgf[64];
  int t=threadIdx.x;
  int blk=blockIdx.x, b=blk/288, tile=blk-b*288, hw0=tile*128;
  if(t<64) sgf[t]=0.f;
  // batched staging loads (4 outstanding uint4 = 8 bf16 each)
  uint4 v[4];
  #pragma unroll
  for(int k=0;k<4;k++){
    int i=t+k*256; int c=i>>4, o=i&15;
    v[k]=*(const uint4*)&h2b[(size_t)(b*64+c)*36864 + hw0 + o*8];
  }
  #pragma unroll
  for(int k=0;k<4;k++){
    int i=t+k*256; int c=i>>4, o=i&15;
    float2 s=sb[b*64+c];
    int sw=((o>>1)&3)<<3, cc=c^sw;
    const unsigned short* pv=(const unsigned short*)&v[k];
    #pragma unroll
    for(int r=0;r<8;r++)
      A[(o*8+r)*72+cc]=f2b(fmaf(b2f(pv[r]),s.x,s.y));
  }
  __syncthreads();
  int wave=t>>6, l=t&63, lr=l&15, lg=l>>4;
  int pxb=wave*32;
  bf8v af[2][2];
  #pragma unroll
  for(int fm=0;fm<2;fm++){
    int row=pxb+fm*16+lr, sw=((row>>4)&3)<<3;
    #pragma unroll
    for(int ks=0;ks<2;ks++) af[fm][ks]=*(const bf8v*)&A[row*72+((ks*32+lg*8)^sw)];
  }
  float gsum[4]={0.f,0.f,0.f,0.f};
  #pragma unroll
  for(int fn=0;fn<4;fn++){
    bf8v b0=*(const bf8v*)(wfe+(fn*16+lr)*64+lg*8);
    bf8v b1=*(const bf8v*)(wfe+(fn*16+lr)*64+32+lg*8);
    float bs=feb[fn*16+lr];
    #pragma unroll
    for(int fm=0;fm<2;fm++){
      f4v acc={0.f,0.f,0.f,0.f};
      acc=MFMA(af[fm][0],b0,acc);
      acc=MFMA(af[fm][1],b1,acc);
      int swm=(((pxb+fm*16)>>4)&3)<<3;
      int cc=(fn*16+lr)^swm;
      #pragma unroll
      for(int r=0;r<4;r++){
        float g=gelu_fast(acc[r]+bs);
        gsum[fn]+=g;
        A[(pxb+fm*16+4*lg+r)*72+cc]=f2b(g);   // wave-private rows
      }
    }
  }
  #pragma unroll
  for(int fn=0;fn<4;fn++){
    float v2=gsum[fn];
    v2+=__shfl_xor(v2,16); v2+=__shfl_xor(v2,32);
    if(lg==0) atomicAdd(&sgf[fn*16+lr], v2);
  }
  __syncthreads();
  if(t<64) atomicAdd(&gfp[b*64+t], sgf[t]);
  // store feats tile bf16 (coalesced: 128B contiguous per 8 threads)
  #pragma unroll
  for(int k=0;k<4;k++){
    int i=t+k*256; int px=i>>3, c0=(i&7)*8, sw=((px>>4)&3)<<3;
    *(uint4*)&feats[(size_t)(b*36864+hw0+px)*64+c0] = *(const uint4*)&A[px*72+(c0^sw)];
  }
}

// ---------------- gating MLP + top-4 softmax -> active-term list ----------
__global__ __launch_bounds__(128) void gating(const float* __restrict__ gfp,
  const float* __restrict__ g1w, const float* __restrict__ g1b,
  const float* __restrict__ bn1g, const float* __restrict__ bn1b, const float* __restrict__ bn1m, const float* __restrict__ bn1v,
  const float* __restrict__ cw1, const float* __restrict__ cb1, const float* __restrict__ cw2, const float* __restrict__ cb2,
  const float* __restrict__ g2w, const float* __restrict__ g2b,
  const float* __restrict__ bn2g, const float* __restrict__ bn2b, const float* __restrict__ bn2m, const float* __restrict__ bn2v,
  const float* __restrict__ g3w, const float* __restrict__ g3b, float2* __restrict__ act){
  __shared__ float gf[8][64];
  __shared__ float h1[8][128];
  __shared__ float a1[8][8];
  __shared__ float h2g[8][64];
  __shared__ float sc[8][16];
  int t=threadIdx.x;
  for(int i=t;i<512;i+=128) gf[i>>6][i&63]=gfp[i]*(1.0f/36864.0f);
  __syncthreads();
  for(int i=t;i<1024;i+=128){
    int b=i>>7, j=i&127;
    float s=g1b[j];
    for(int c=0;c<64;c++) s=fmaf(gf[b][c], g1w[j*64+c], s);
    s=(s-bn1m[j])*rsqrtf(bn1v[j]+1e-5f)*bn1g[j]+bn1b[j];
    h1[b][j]=gelu_f(s);
  }
  __syncthreads();
  if(t<64){
    int b=t>>3, k=t&7; float s=cb1[k];
    for(int j=0;j<128;j++) s=fmaf(h1[b][j], cw1[k*128+j], s);
    a1[b][k]=gelu_f(s);
  }
  __syncthreads();
  for(int i=t;i<1024;i+=128){
    int b=i>>7, j=i&127;
    float s=cb2[j];
    for(int k=0;k<8;k++) s=fmaf(a1[b][k], cw2[j*8+k], s);
    h1[b][j]=h1[b][j]/(1.0f+expf(-2.0f*s));
  }
  __syncthreads();
  for(int i=t;i<512;i+=128){
    int b=i>>6, j=i&63;
    float s=g2b[j];
    for(int k=0;k<128;k++) s=fmaf(h1[b][k], g2w[j*128+k], s);
    s=(s-bn2m[j])*rsqrtf(bn2v[j]+1e-5f)*bn2g[j]+bn2b[j];
    h2g[b][j]=gelu_f(s);
  }
  __syncthreads();
  {
    int b=t>>4, e=t&15;
    float s=g3b[e];
    for(int c=0;c<64;c++) s=fmaf(h2g[b][c], g3w[e*64+c], s);
    sc[b][e]=s;
  }
  __syncthreads();
  if(t<8){
    int b=t;
    float v[16];
    for(int e=0;e<16;e++) v[e]=sc[b][e];
    float vals[4]; int idx[4];
    for(int k=0;k<4;k++){
      float best=-1e30f; int bi=0;
      for(int e=0;e<16;e++) if(v[e]>best){best=v[e];bi=e;}
      vals[k]=best; idx[k]=bi; v[bi]=-1e30f;
    }
    float m=vals[0], ssum=0.f, w[4];
    for(int k=0;k<4;k++){ w[k]=expf((vals[k]-m)*0.5f); ssum+=w[k]; }
    act[b*6+0]=make_float2(0.5f, __int_as_float(0));
    act[b*6+1]=make_float2(0.5f, __int_as_float(1));
    for(int k=0;k<4;k++) act[b*6+2+k]=make_float2(w[k]/ssum, __int_as_float(2+idx[k]));
  }
}

// ---------------- experts: Fo repack + pure full-line stores --------------
// Direct-fragment feats loads, act preloaded, bf16 residual read in the
// repack epilogue (256B contiguous per oc half-row). Stores are pure and
// full-line (R10/R12/R15 lesson: never partial-line, never split RMW).
__global__ __launch_bounds__(256,4) void final_k(const unsigned short* __restrict__ feats,
  const unsigned short* __restrict__ h2b,
  const unsigned short* __restrict__ wall, const float* __restrict__ ball,
  const float2* __restrict__ act, float* __restrict__ out){
  __shared__ __align__(16) float Fo[32*132];   // 16896 B
  int t=threadIdx.x;
  int blk=blockIdx.x, b=blk/288, tile=blk-b*288, hw0=tile*128;
  int wave=t>>6, l=t&63, lr=l&15, lg=l>>4;
  int pxb=wave*32;
  // preload active-term list (uniform per b)
  float gv[6]; int tv[6];
  #pragma unroll
  for(int j=0;j<6;j++){
    float2 aw=act[b*6+j];
    gv[j]=aw.x; tv[j]=__float_as_int(aw.y);
  }
  const unsigned short* fbase = feats + (size_t)(b*36864+hw0)*64;
  bf8v af2[2][2];
  #pragma unroll
  for(int fm=0;fm<2;fm++){
    int row=pxb+fm*16+lr;
    #pragma unroll
    for(int ks=0;ks<2;ks++)
      af2[fm][ks]=*(const bf8v*)(fbase + (size_t)row*64 + ks*32 + lg*8);
  }
  // ---- per oc-half: 6 terms -> repack -> coalesced pure store ----
  #pragma unroll
  for(int half=0;half<2;half++){
    float oa[2][2][4]={};       // [fm][fn2][r]
    #pragma unroll
    for(int j=0;j<6;j++){
      float g=gv[j];
      const unsigned short* wp=wall+tv[j]*4096;
      const float* bp=ball+tv[j]*64;
      #pragma unroll
      for(int fn2=0;fn2<2;fn2++){
        int fn=half*2+fn2;
        bf8v b0=*(const bf8v*)(wp+(fn*16+lr)*64+lg*8);
        bf8v b1=*(const bf8v*)(wp+(fn*16+lr)*64+32+lg*8);
        float bs=bp[fn*16+lr];
        #pragma unroll
        for(int fm=0;fm<2;fm++){
          f4v acc={0.f,0.f,0.f,0.f};
          acc=MFMA(af2[fm][0],b0,acc);
          acc=MFMA(af2[fm][1],b1,acc);
          #pragma unroll
          for(int r=0;r<4;r++)
            oa[fm][fn2][r]=fmaf(g, gelu_sig(acc[r]+bs), oa[fm][fn2][r]);
        }
      }
    }
    __syncthreads();            // prev half's Fo reads done (no-op for half 0)
    #pragma unroll
    for(int fm=0;fm<2;fm++)
      #pragma unroll
      for(int fn2=0;fn2<2;fn2++){
        int ocl=fn2*16+lr;
        *(float4*)&Fo[ocl*132 + pxb + fm*16 + 4*lg] =
            make_float4(oa[fm][fn2][0],oa[fm][fn2][1],oa[fm][fn2][2],oa[fm][fn2][3]);
      }
    __syncthreads();
    for(int i=t;i<1024;i+=256){
      int ocl=i>>5, px0=(i&31)*4;
      int oc=half*32+ocl;
      size_t base=(size_t)(b*64+oc)*36864 + hw0 + px0;
      ushort4 hv=*(const ushort4*)&h2b[base];
      float4 ov=*(const float4*)&Fo[ocl*132+px0];
      *(float4*)&out[base]=make_float4(ov.x+b2f(hv.x),ov.y+b2f(hv.y),
                                       ov.z+b2f(hv.z),ov.w+b2f(hv.w));
    }
  }
}

extern "C" void kernel_launch(void* const* d_in, const int* in_sizes, int n_in,
                              void* d_out, int out_size, void* d_ws, size_t ws_size,
                              hipStream_t stream){
  const float* x    =(const float*)d_in[0];
  const float* gn1w =(const float*)d_in[1];
  const float* gn1b =(const float*)d_in[2];
  const float* aw1  =(const float*)d_in[3];
  const float* ab1  =(const float*)d_in[4];
  const float* aw2  =(const float*)d_in[5];
  const float* ab2  =(const float*)d_in[6];
  const float* gn2w =(const float*)d_in[7];
  const float* gn2b =(const float*)d_in[8];
  const float* few  =(const float*)d_in[9];
  const float* feb  =(const float*)d_in[10];
  const float* g1w  =(const float*)d_in[11];
  const float* g1b  =(const float*)d_in[12];
  const float* bn1g =(const float*)d_in[13];
  const float* bn1b =(const float*)d_in[14];
  const float* bn1m =(const float*)d_in[15];
  const float* bn1v =(const float*)d_in[16];
  const float* cw1  =(const float*)d_in[17];
  const float* cb1  =(const float*)d_in[18];
  const float* cw2  =(const float*)d_in[19];
  const float* cb2  =(const float*)d_in[20];
  const float* g2w  =(const float*)d_in[21];
  const float* g2b  =(const float*)d_in[22];
  const float* bn2g =(const float*)d_in[23];
  const float* bn2b =(const float*)d_in[24];
  const float* bn2m =(const float*)d_in[25];
  const float* bn2v =(const float*)d_in[26];
  const float* g3w  =(const float*)d_in[27];
  const float* g3b  =(const float*)d_in[28];
  const float* shw  =(const float*)d_in[29];
  const float* shb  =(const float*)d_in[30];
  const float* exw  =(const float*)d_in[31];
  const float* exb  =(const float*)d_in[32];

  float* out=(float*)d_out;
  float* ws=(float*)d_ws;

  // workspace layout (float offsets)
  float*  part1 = ws;                         // 1024
  float*  part2 = ws+1024;                    // 1024
  float2* sb1   = (float2*)(ws+2048);         // 512 float2
  float2* sb2   = (float2*)(ws+3072);         // 512 float2
  float2* act   = (float2*)(ws+4096);         // 48 float2
  float*  gfp   = ws+4224;                    // 512
  float*  Xm2   = ws+8192;                    // 1048576
  float*  S2    = ws+1056768;                 // 1048576
  unsigned short* Tbl  = (unsigned short*)(ws+2105344);  // 61440 shorts
  unsigned short* wall = (unsigned short*)(ws+2136064);  // 73728 shorts
  float*          ball = ws+2172928;                     // 1152
  unsigned short* wfe  = (unsigned short*)(ws+2174080);  // 4096 shorts
  unsigned short* feats= (unsigned short*)(ws+2176128);  // 18874368 shorts (~37.7MB)
  unsigned short* h2b  = (unsigned short*)(ws+11613312); // 18874368 shorts (~37.7MB)
  const unsigned short* TBf1 = Tbl;
  const unsigned short* TBf2 = Tbl+12288;
  const unsigned short* TAi  = Tbl+36864;
  const unsigned short* TBi  = Tbl+49152;

  prep<<<64,256,0,stream>>>(shw, exw, shb, exb, few, Tbl, wall, ball, wfe, gfp);
  // AFNO on raw x (gn1 via linearity), emits gn1 stats
  fwd_dft <<<512,256,0,stream>>>(x, TBf1, TBf2, Xm2, part1);
  gn_finalize<<<1,64,0,stream>>>(part1, gn1w, gn1b, sb1);
  mode_mlp<<<256,256,0,stream>>>(Xm2, sb1, aw1, ab1, aw2, ab2, S2);
  inv_dft <<<512,256,0,stream>>>(S2, TAi, TBi, x, sb1, h2b, part2); // h2 -> bf16 workspace
  gn_finalize<<<1,64,0,stream>>>(part2, gn2w, gn2b, sb2);
  // gating means + feats materialization (bf16 in/out)
  gf_k<<<2304,256,0,stream>>>(h2b, sb2, wfe, feb, gfp, feats);
  gating <<<1,128,0,stream>>>(gfp, g1w,g1b, bn1g,bn1b,bn1m,bn1v,
                              cw1,cb1,cw2,cb2, g2w,g2b, bn2g,bn2b,bn2m,bn2v,
                              g3w,g3b, act);
  // experts: Fo repack + pure full-line stores (residual from bf16 h2b)
  final_k<<<2304,256,0,stream>>>(feats, h2b, wall, ball, act, out);
}

// Round 17
// 202.535 us; speedup vs baseline: 1.1221x; 1.0115x over previous
//
#include <hip/hip_runtime.h>
#include <math.h>

// Problem constants: B=8, C=64, H=W=192, HW=36864, MODES=32, NB=4, BS=16, E=16
#define TPI 6.283185307179586f

typedef __attribute__((ext_vector_type(8))) short bf8v;   // 8 bf16 (4 VGPRs)
typedef __attribute__((ext_vector_type(4))) float f4v;    // 4 fp32 acc

#define MFMA(a,b,c) __builtin_amdgcn_mfma_f32_16x16x32_bf16((a),(b),(c),0,0,0)

__device__ __forceinline__ float gelu_f(float v){          // exact (erf)
  return 0.5f*v*(1.0f+erff(v*0.7071067811865475f));
}
// tanh-form gelu via fast exp + fast rcp (no IEEE div): err ~5e-4 abs
__device__ __forceinline__ float gelu_fast(float x){
  float x2=x*x;
  float inner=fmaf(0.044715f*x2, x, x);
  float e=__expf(1.5957691216057308f*inner);   // exp(2*0.7978845608*inner)
  float r=__builtin_amdgcn_rcpf(1.0f+e);
  return fmaf(-x, r, x);                        // x*(1-r)
}
// sigmoid-form gelu: x*sigmoid(1.702x). err <= ~0.0203 abs
__device__ __forceinline__ float gelu_sig(float x){
  float e=__expf(-1.702f*x);
  return x*__builtin_amdgcn_rcpf(1.0f+e);
}
__device__ __forceinline__ unsigned short f2b(float f){   // f32 -> bf16 (RNE)
  union{float f; unsigned u;} v; v.f=f;
  unsigned r=v.u + 0x7FFFu + ((v.u>>16)&1u);
  return (unsigned short)(r>>16);
}
__device__ __forceinline__ float b2f(unsigned short h){
  union{unsigned u; float f;} v; v.u=((unsigned)h)<<16; return v.f;
}

// ---------------- prep: twiddle tables + bf16 weights + zero gfp -----------
__global__ __launch_bounds__(256) void prep(const float* __restrict__ shw, const float* __restrict__ exw,
    const float* __restrict__ shb, const float* __restrict__ exb, const float* __restrict__ few,
    unsigned short* __restrict__ T, unsigned short* __restrict__ wall, float* __restrict__ ball,
    unsigned short* __restrict__ wfe, float* __restrict__ gfp){
  const float a = TPI/192.0f;
  int stride=gridDim.x*256;
  for(int i=blockIdx.x*256+threadIdx.x; i<61440; i+=stride){
    float v;
    if(i<12288){
      int n1=i/192, w=i%192; int kw=n1>>1, c=n1&1;
      int m=(kw*w)%192; float cs,sn; sincosf((float)m*a,&sn,&cs);
      v = c ? -sn : cs;
    } else if(i<36864){
      int j=i-12288; int n1=j/384, k1=j%384; int kh=n1>>1, d=n1&1; int h=k1>>1, c=k1&1;
      int m=(kh*h)%192; float cs,sn; sincosf((float)m*a,&sn,&cs);
      float e = d ? (c ? cs : -sn) : (c ? sn : cs);
      v = e*(1.0f/192.0f);
    } else if(i<49152){
      int j=i-36864; int h=j/64, k1=j%64; int kh=k1>>1, c=k1&1;
      int m=(h*kh)%192; float cs,sn; sincosf((float)m*a,&sn,&cs);
      v = c ? sn : cs;
    } else {
      int j=i-49152; int w=j/64, k1=j%64; int kw=k1>>1, d=k1&1;
      float f = kw ? (2.0f/192.0f) : (1.0f/192.0f);
      int m=(w*kw)%192; float cs,sn; sincosf((float)m*a,&sn,&cs);
      v = d ? -f*sn : f*cs;
    }
    T[i]=f2b(v);
  }
  for(int i=blockIdx.x*256+threadIdx.x;i<73728;i+=stride) wall[i]=f2b(i<8192?shw[i]:exw[i-8192]);
  for(int i=blockIdx.x*256+threadIdx.x;i<1152;i+=stride)  ball[i]=(i<128)?shb[i]:exb[i-128];
  for(int i=blockIdx.x*256+threadIdx.x;i<4096;i+=stride)  wfe[i]=f2b(few[i]);
  for(int i=blockIdx.x*256+threadIdx.x;i<512;i+=stride)   gfp[i]=0.f;
}

__global__ void gn_finalize(const float* __restrict__ part, const float* __restrict__ gw,
                            const float* __restrict__ gb, float2* __restrict__ sb){
  int g=threadIdx.x; if(g>=64) return;
  float S=0,SS=0;
  for(int j=0;j<8;j++){ S+=part[(g*8+j)*2]; SS+=part[(g*8+j)*2+1]; }
  const float inv=1.0f/294912.0f;
  float mean=S*inv, var=SS*inv-mean*mean;
  float rstd=rsqrtf(var+1e-5f);
  int b=g>>3, gg=g&7;
  for(int k=0;k<8;k++){
    int c=gg*8+k;
    float sc=rstd*gw[c];
    sb[b*64+c]=make_float2(sc, gb[c]-mean*sc);
  }
}

// ---------------- fwd DFT on RAW x (gn1 folded out via linearity) ---------
__global__ __launch_bounds__(256) void fwd_dft(const float* __restrict__ x,
      const unsigned short* __restrict__ TBf1, const unsigned short* __restrict__ TBf2,
      float* __restrict__ Xm2, float* __restrict__ part1){
  __shared__ __align__(16) unsigned short ldsA[64*200];  // Bt1 [64][200]; later tL [32][392]
  __shared__ __align__(16) float sX[2048];
  __shared__ float red[8];
  int t=threadIdx.x, bc=blockIdx.x;
  int wave=t>>6, l=t&63, lr=l&15, lg=l>>4;
  const float* xch = x + (size_t)bc*36864;
  for(int i=t;i<1536;i+=256){
    int row=i/24, chunk=i%24;
    *(uint4*)&ldsA[row*200 + chunk*8] = *(const uint4*)(TBf1 + row*192 + chunk*8);
  }
  __syncthreads();
  float s_=0.f, ss_=0.f;
  // ---- stage 1 ----
  f4v acc1[3][4];
  for(int mt=0;mt<3;mt++){
    int m0=(wave+mt*4)*16;
    const float* xrow = xch + (m0+lr)*192 + lg*8;
    bf8v af[6];
    #pragma unroll
    for(int ks=0;ks<6;ks++){
      float4 u0=*(const float4*)(xrow+ks*32);
      float4 u1=*(const float4*)(xrow+ks*32+4);
      s_ += u0.x+u0.y+u0.z+u0.w+u1.x+u1.y+u1.z+u1.w;
      ss_+= u0.x*u0.x+u0.y*u0.y+u0.z*u0.z+u0.w*u0.w
           +u1.x*u1.x+u1.y*u1.y+u1.z*u1.z+u1.w*u1.w;
      bf8v a;
      a[0]=(short)f2b(u0.x); a[1]=(short)f2b(u0.y); a[2]=(short)f2b(u0.z); a[3]=(short)f2b(u0.w);
      a[4]=(short)f2b(u1.x); a[5]=(short)f2b(u1.y); a[6]=(short)f2b(u1.z); a[7]=(short)f2b(u1.w);
      af[ks]=a;
    }
    #pragma unroll
    for(int nt=0;nt<4;nt++){
      f4v acc={0.f,0.f,0.f,0.f};
      #pragma unroll
      for(int ks=0;ks<6;ks++){
        bf8v b=*(const bf8v*)&ldsA[(nt*16+lr)*200 + ks*32 + lg*8];
        acc=MFMA(af[ks],b,acc);
      }
      acc1[mt][nt]=acc;
    }
  }
  __syncthreads();            // reuse ldsA as tL [32][392]
  for(int mt=0;mt<3;mt++){
    int m0=(wave+mt*4)*16;
    #pragma unroll
    for(int nt=0;nt<4;nt++){
      int n1=nt*16+lr; int kw=n1>>1, c=n1&1;
      #pragma unroll
      for(int reg=0;reg<4;reg++){
        int h=m0+4*lg+reg;
        ldsA[kw*392 + 2*h + c]=f2b(acc1[mt][nt][reg]);
      }
    }
  }
  __syncthreads();
  // ---- stage 2 ----
  for(int pp=0;pp<2;pp++){
    int p=wave+pp*4;
    int m0=(p>>2)*16, n0=(p&3)*16;
    f4v acc={0.f,0.f,0.f,0.f};
    #pragma unroll
    for(int ks=0;ks<12;ks++){
      bf8v a=*(const bf8v*)&ldsA[(m0+lr)*392 + ks*32 + lg*8];
      bf8v b=*(const bf8v*)(TBf2 + (n0+lr)*384 + ks*32 + lg*8);
      acc=MFMA(a,b,acc);
    }
    int n1=n0+lr; int kh=n1>>1, d=n1&1;
    #pragma unroll
    for(int reg=0;reg<4;reg++){
      int kw=m0+4*lg+reg;
      sX[(kh*32+kw)*2 + d]=acc[reg];
    }
  }
  __syncthreads();
  float* dst=Xm2+(size_t)bc*2048;
  for(int i=t;i<512;i+=256) *(float4*)(dst+i*4)=*(const float4*)(sX+i*4);
  // ---- gn1 stats ----
  #pragma unroll
  for(int o=32;o>0;o>>=1){ s_+=__shfl_down(s_,o); ss_+=__shfl_down(ss_,o); }
  if(l==0){ red[wave]=s_; red[4+wave]=ss_; }
  __syncthreads();
  if(t==0){
    part1[bc*2]  =red[0]+red[1]+red[2]+red[3];
    part1[bc*2+1]=red[4]+red[5]+red[6]+red[7];
  }
}

// ---------------- block-diagonal complex 2-layer MLP on modes -------------
__global__ __launch_bounds__(256) void mode_mlp(const float* __restrict__ Xm2, const float2* __restrict__ sb1,
    const float* __restrict__ w1, const float* __restrict__ b1,
    const float* __restrict__ w2, const float* __restrict__ b2,
    float* __restrict__ S2){
  __shared__ float w10[1024], w11[1024], w20[1024], w21[1024];
  __shared__ float b10[64], b11[64], b20[64], b21[64];
  __shared__ float2 sbl[64];
  __shared__ float xr[32][64], xi[32][64];
  __shared__ float o1r[32][64], o1i[32][64];
  int t=threadIdx.x;
  int b=blockIdx.x>>5, kh=blockIdx.x&31;
  for(int i=t;i<1024;i+=256){ w10[i]=w1[i]; w11[i]=w1[1024+i]; w20[i]=w2[i]; w21[i]=w2[1024+i]; }
  if(t<64){ b10[t]=b1[t]; b11[t]=b1[64+t]; b20[t]=b2[t]; b21[t]=b2[64+t]; sbl[t]=sb1[b*64+t]; }
  __syncthreads();
  for(int q=0;q<16;q++){
    int idx=q*256+t; int c=idx>>6, jj=idx&63;
    float2 s=sbl[c];
    float v=Xm2[((size_t)(b*64+c))*2048 + kh*64 + jj]*s.x;
    if(kh==0 && jj==0) v += 192.0f*s.y;
    if(jj&1) xi[jj>>1][c]=v; else xr[jj>>1][c]=v;
  }
  __syncthreads();
  int tl=t&63, n=tl>>4, o=tl&15, wb=n*256+o;
  #pragma unroll
  for(int it=0;it<8;it++){
    int kw=(t>>6)+it*4;
    float a_r=b10[tl], a_i=b11[tl];
    #pragma unroll
    for(int i=0;i<16;i++){
      float rr=xr[kw][n*16+i], im=xi[kw][n*16+i];
      float W0=w10[wb+i*16], W1=w11[wb+i*16];
      a_r=fmaf(rr,W0,fmaf(-im,W1,a_r));
      a_i=fmaf(im,W0,fmaf( rr,W1,a_i));
    }
    o1r[kw][tl]=gelu_f(a_r); o1i[kw][tl]=gelu_f(a_i);
  }
  __syncthreads();
  #pragma unroll
  for(int it=0;it<8;it++){
    int kw=(t>>6)+it*4;
    float c_r=b20[tl], c_i=b21[tl];
    #pragma unroll
    for(int i=0;i<16;i++){
      float rr=o1r[kw][n*16+i], im=o1i[kw][n*16+i];
      float W0=w20[wb+i*16], W1=w21[wb+i*16];
      c_r=fmaf(rr,W0,fmaf(-im,W1,c_r));
      c_i=fmaf(im,W0,fmaf( rr,W1,c_i));
    }
    xr[kw][tl]=c_r; xi[kw][tl]=c_i;
  }
  __syncthreads();
  for(int q=0;q<16;q++){
    int idx=q*256+t; int c=idx>>6, jj=idx&63;
    float v = (jj&1) ? xi[jj>>1][c] : xr[jj>>1][c];
    S2[((size_t)(b*64+c))*2048 + kh*64 + jj]=v;
  }
}

// ---------------- inverse DFT + residuals + gn2 stats (h2 -> bf16) --------
__global__ __launch_bounds__(256) void inv_dft(const float* __restrict__ S2,
      const unsigned short* __restrict__ TAi, const unsigned short* __restrict__ TBi,
      const float* __restrict__ x, const float2* __restrict__ sb,
      unsigned short* __restrict__ h2b, float* __restrict__ part2){
  __shared__ __align__(16) unsigned short Bs[64*72];
  __shared__ __align__(16) unsigned short GL[192*72];
  __shared__ float red[8];
  int t=threadIdx.x, bc=blockIdx.x;
  int wave=t>>6, l=t&63, lr=l&15, lg=l>>4;
  const float* sp=S2+(size_t)bc*2048;
  for(int i=t;i<1024;i+=256){
    int kh=i>>5, kw=i&31;
    float Sr=sp[(kh*32+kw)*2], Si=sp[(kh*32+kw)*2+1];
    unsigned short br=f2b(Sr), bi_=f2b(Si), nbi=f2b(-Si);
    Bs[(2*kw+0)*72 + 2*kh+0]=br;
    Bs[(2*kw+0)*72 + 2*kh+1]=nbi;
    Bs[(2*kw+1)*72 + 2*kh+0]=bi_;
    Bs[(2*kw+1)*72 + 2*kh+1]=br;
  }
  __syncthreads();
  for(int mt=0;mt<3;mt++){
    int m0=(wave+mt*4)*16;
    bf8v a0=*(const bf8v*)(TAi + (m0+lr)*64 + lg*8);
    bf8v a1=*(const bf8v*)(TAi + (m0+lr)*64 + 32 + lg*8);
    #pragma unroll
    for(int nt=0;nt<4;nt++){
      f4v acc={0.f,0.f,0.f,0.f};
      bf8v b0=*(const bf8v*)&Bs[(nt*16+lr)*72 + lg*8];
      bf8v b1=*(const bf8v*)&Bs[(nt*16+lr)*72 + 32 + lg*8];
      acc=MFMA(a0,b0,acc); acc=MFMA(a1,b1,acc);
      #pragma unroll
      for(int reg=0;reg<4;reg++)
        GL[(m0+4*lg+reg)*72 + nt*16+lr]=f2b(acc[reg]);
    }
  }
  __syncthreads();
  float2 sv=sb[bc];
  float cA=sv.x+1.0f, cB=sv.y;
  asm volatile("" : "+v"(cA), "+v"(cB));   // pin to VGPR (constant-bus fix)
  const float* xch=x+(size_t)bc*36864;
  unsigned short* och=h2b+(size_t)bc*36864;
  float s_=0.f, ss_=0.f;
  for(int mt=0;mt<3;mt++){
    int m0=(wave+mt*4)*16;
    bf8v a0=*(const bf8v*)&GL[(m0+lr)*72 + lg*8];
    bf8v a1=*(const bf8v*)&GL[(m0+lr)*72 + 32 + lg*8];
    for(int nt=0;nt<12;nt++){
      int n0=nt*16;
      f4v acc={0.f,0.f,0.f,0.f};
      bf8v b0=*(const bf8v*)(TBi + (n0+lr)*64 + lg*8);
      bf8v b1=*(const bf8v*)(TBi + (n0+lr)*64 + 32 + lg*8);
      acc=MFMA(a0,b0,acc); acc=MFMA(a1,b1,acc);
      int w=n0+lr;
      #pragma unroll
      for(int reg=0;reg<4;reg++){
        int h=m0+4*lg+reg;
        int ga=h*192+w;
        float xv=xch[ga];
        float val=acc[reg]+fmaf(cA,xv,cB);
        och[ga]=f2b(val);
        s_+=val; ss_+=val*val;
      }
    }
  }
  #pragma unroll
  for(int o=32;o>0;o>>=1){ s_+=__shfl_down(s_,o); ss_+=__shfl_down(ss_,o); }
  if(l==0){ red[wave]=s_; red[4+wave]=ss_; }
  __syncthreads();
  if(t==0){
    part2[bc*2]  =red[0]+red[1]+red[2]+red[3];
    part2[bc*2+1]=red[4]+red[5]+red[6]+red[7];
  }
}

// ---------------- gf_k: gating means + feats materialization (bf16 in) ----
__global__ __launch_bounds__(256,4) void gf_k(const unsigned short* __restrict__ h2b, const float2* __restrict__ sb,
    const unsigned short* __restrict__ wfe, const float* __restrict__ feb,
    float* __restrict__ gfp, unsigned short* __restrict__ feats){
  __shared__ __align__(16) unsigned short A[128*72];
  __shared__ float sgf[64];
  int t=threadIdx.x;
  int blk=blockIdx.x, b=blk/288, tile=blk-b*288, hw0=tile*128;
  if(t<64) sgf[t]=0.f;
  // batched staging loads (4 outstanding uint4 = 8 bf16 each)
  uint4 v[4];
  #pragma unroll
  for(int k=0;k<4;k++){
    int i=t+k*256; int c=i>>4, o=i&15;
    v[k]=*(const uint4*)&h2b[(size_t)(b*64+c)*36864 + hw0 + o*8];
  }
  #pragma unroll
  for(int k=0;k<4;k++){
    int i=t+k*256; int c=i>>4, o=i&15;
    float2 s=sb[b*64+c];
    int sw=((o>>1)&3)<<3, cc=c^sw;
    const unsigned short* pv=(const unsigned short*)&v[k];
    #pragma unroll
    for(int r=0;r<8;r++)
      A[(o*8+r)*72+cc]=f2b(fmaf(b2f(pv[r]),s.x,s.y));
  }
  __syncthreads();
  int wave=t>>6, l=t&63, lr=l&15, lg=l>>4;
  int pxb=wave*32;
  bf8v af[2][2];
  #pragma unroll
  for(int fm=0;fm<2;fm++){
    int row=pxb+fm*16+lr, sw=((row>>4)&3)<<3;
    #pragma unroll
    for(int ks=0;ks<2;ks++) af[fm][ks]=*(const bf8v*)&A[row*72+((ks*32+lg*8)^sw)];
  }
  float gsum[4]={0.f,0.f,0.f,0.f};
  #pragma unroll
  for(int fn=0;fn<4;fn++){
    bf8v b0=*(const bf8v*)(wfe+(fn*16+lr)*64+lg*8);
    bf8v b1=*(const bf8v*)(wfe+(fn*16+lr)*64+32+lg*8);
    float bs=feb[fn*16+lr];
    #pragma unroll
    for(int fm=0;fm<2;fm++){
      f4v acc={0.f,0.f,0.f,0.f};
      acc=MFMA(af[fm][0],b0,acc);
      acc=MFMA(af[fm][1],b1,acc);
      int swm=(((pxb+fm*16)>>4)&3)<<3;
      int cc=(fn*16+lr)^swm;
      #pragma unroll
      for(int r=0;r<4;r++){
        float g=gelu_fast(acc[r]+bs);
        gsum[fn]+=g;
        A[(pxb+fm*16+4*lg+r)*72+cc]=f2b(g);   // wave-private rows
      }
    }
  }
  #pragma unroll
  for(int fn=0;fn<4;fn++){
    float v2=gsum[fn];
    v2+=__shfl_xor(v2,16); v2+=__shfl_xor(v2,32);
    if(lg==0) atomicAdd(&sgf[fn*16+lr], v2);
  }
  __syncthreads();
  if(t<64) atomicAdd(&gfp[b*64+t], sgf[t]);
  // store feats tile bf16 (coalesced: 128B contiguous per 8 threads)
  #pragma unroll
  for(int k=0;k<4;k++){
    int i=t+k*256; int px=i>>3, c0=(i&7)*8, sw=((px>>4)&3)<<3;
    *(uint4*)&feats[(size_t)(b*36864+hw0+px)*64+c0] = *(const uint4*)&A[px*72+(c0^sw)];
  }
}

// ---------------- gating MLP + top-4 softmax -> active-term list ----------
__global__ __launch_bounds__(128) void gating(const float* __restrict__ gfp,
  const float* __restrict__ g1w, const float* __restrict__ g1b,
  const float* __restrict__ bn1g, const float* __restrict__ bn1b, const float* __restrict__ bn1m, const float* __restrict__ bn1v,
  const float* __restrict__ cw1, const float* __restrict__ cb1, const float* __restrict__ cw2, const float* __restrict__ cb2,
  const float* __restrict__ g2w, const float* __restrict__ g2b,
  const float* __restrict__ bn2g, const float* __restrict__ bn2b, const float* __restrict__ bn2m, const float* __restrict__ bn2v,
  const float* __restrict__ g3w, const float* __restrict__ g3b, float2* __restrict__ act){
  __shared__ float gf[8][64];
  __shared__ float h1[8][128];
  __shared__ float a1[8][8];
  __shared__ float h2g[8][64];
  __shared__ float sc[8][16];
  int t=threadIdx.x;
  for(int i=t;i<512;i+=128) gf[i>>6][i&63]=gfp[i]*(1.0f/36864.0f);
  __syncthreads();
  for(int i=t;i<1024;i+=128){
    int b=i>>7, j=i&127;
    float s=g1b[j];
    for(int c=0;c<64;c++) s=fmaf(gf[b][c], g1w[j*64+c], s);
    s=(s-bn1m[j])*rsqrtf(bn1v[j]+1e-5f)*bn1g[j]+bn1b[j];
    h1[b][j]=gelu_f(s);
  }
  __syncthreads();
  if(t<64){
    int b=t>>3, k=t&7; float s=cb1[k];
    for(int j=0;j<128;j++) s=fmaf(h1[b][j], cw1[k*128+j], s);
    a1[b][k]=gelu_f(s);
  }
  __syncthreads();
  for(int i=t;i<1024;i+=128){
    int b=i>>7, j=i&127;
    float s=cb2[j];
    for(int k=0;k<8;k++) s=fmaf(a1[b][k], cw2[j*8+k], s);
    h1[b][j]=h1[b][j]/(1.0f+expf(-2.0f*s));
  }
  __syncthreads();
  for(int i=t;i<512;i+=128){
    int b=i>>6, j=i&63;
    float s=g2b[j];
    for(int k=0;k<128;k++) s=fmaf(h1[b][k], g2w[j*128+k], s);
    s=(s-bn2m[j])*rsqrtf(bn2v[j]+1e-5f)*bn2g[j]+bn2b[j];
    h2g[b][j]=gelu_f(s);
  }
  __syncthreads();
  {
    int b=t>>4, e=t&15;
    float s=g3b[e];
    for(int c=0;c<64;c++) s=fmaf(h2g[b][c], g3w[e*64+c], s);
    sc[b][e]=s;
  }
  __syncthreads();
  if(t<8){
    int b=t;
    float v[16];
    for(int e=0;e<16;e++) v[e]=sc[b][e];
    float vals[4]; int idx[4];
    for(int k=0;k<4;k++){
      float best=-1e30f; int bi=0;
      for(int e=0;e<16;e++) if(v[e]>best){best=v[e];bi=e;}
      vals[k]=best; idx[k]=bi; v[bi]=-1e30f;
    }
    float m=vals[0], ssum=0.f, w[4];
    for(int k=0;k<4;k++){ w[k]=expf((vals[k]-m)*0.5f); ssum+=w[k]; }
    act[b*6+0]=make_float2(0.5f, __int_as_float(0));
    act[b*6+1]=make_float2(0.5f, __int_as_float(1));
    for(int k=0;k<4;k++) act[b*6+2+k]=make_float2(w[k]/ssum, __int_as_float(2+idx[k]));
  }
}

// ---------------- experts: 1-wave blocks, zero barriers -------------------
// Each 64-thread block owns a 32px x 64oc tile. Wave-private Fo (in-wave LDS
// ordering = program order, no __syncthreads). Full-line stores (128B
// contiguous aligned per oc row). Residual from bf16 h2b (pure stores).
__global__ __launch_bounds__(64,4) void final_k(const unsigned short* __restrict__ feats,
  const unsigned short* __restrict__ h2b,
  const unsigned short* __restrict__ wall, const float* __restrict__ ball,
  const float2* __restrict__ act, float* __restrict__ out){
  __shared__ __align__(16) float Fo[32*36];   // [ocl][px], 4608 B
  int l=threadIdx.x, lr=l&15, lg=l>>4;
  int blk=blockIdx.x, b=blk/1152, rem=blk-b*1152, hw0=rem*32;
  // preload active-term list (uniform per b)
  float gv[6]; int tv[6];
  #pragma unroll
  for(int j=0;j<6;j++){
    float2 aw=act[b*6+j];
    gv[j]=aw.x; tv[j]=__float_as_int(aw.y);
  }
  const unsigned short* fbase = feats + (size_t)(b*36864+hw0)*64;
  bf8v af2[2][2];
  #pragma unroll
  for(int fm=0;fm<2;fm++){
    int row=fm*16+lr;
    #pragma unroll
    for(int ks=0;ks<2;ks++)
      af2[fm][ks]=*(const bf8v*)(fbase + (size_t)row*64 + ks*32 + lg*8);
  }
  // ---- per oc-half: 6 terms -> wave-private repack -> pure store ----
  #pragma unroll
  for(int half=0;half<2;half++){
    float oa[2][2][4]={};       // [fm][fn2][r]
    #pragma unroll
    for(int j=0;j<6;j++){
      float g=gv[j];
      const unsigned short* wp=wall+tv[j]*4096;
      const float* bp=ball+tv[j]*64;
      #pragma unroll
      for(int fn2=0;fn2<2;fn2++){
        int fn=half*2+fn2;
        bf8v b0=*(const bf8v*)(wp+(fn*16+lr)*64+lg*8);
        bf8v b1=*(const bf8v*)(wp+(fn*16+lr)*64+32+lg*8);
        float bs=bp[fn*16+lr];
        #pragma unroll
        for(int fm=0;fm<2;fm++){
          f4v acc={0.f,0.f,0.f,0.f};
          acc=MFMA(af2[fm][0],b0,acc);
          acc=MFMA(af2[fm][1],b1,acc);
          #pragma unroll
          for(int r=0;r<4;r++)
            oa[fm][fn2][r]=fmaf(g, gelu_sig(acc[r]+bs), oa[fm][fn2][r]);
        }
      }
    }
    // wave-private repack (no barrier: same-wave LDS is program-ordered)
    #pragma unroll
    for(int fm=0;fm<2;fm++)
      #pragma unroll
      for(int fn2=0;fn2<2;fn2++){
        int ocl=fn2*16+lr;
        *(float4*)&Fo[ocl*36 + fm*16 + 4*lg] =
            make_float4(oa[fm][fn2][0],oa[fm][fn2][1],oa[fm][fn2][2],oa[fm][fn2][3]);
      }
    // coalesced pure stores: 8 threads x float4 = 128B contiguous per oc row
    #pragma unroll
    for(int k=0;k<4;k++){
      int idx=l+64*k;             // 0..255
      int ocl=idx>>3, q=idx&7;
      int oc=half*32+ocl;
      size_t base=(size_t)(b*64+oc)*36864 + hw0 + q*4;
      ushort4 hv=*(const ushort4*)&h2b[base];
      float4 ov=*(const float4*)&Fo[ocl*36+q*4];
      *(float4*)&out[base]=make_float4(ov.x+b2f(hv.x),ov.y+b2f(hv.y),
                                       ov.z+b2f(hv.z),ov.w+b2f(hv.w));
    }
  }
}

extern "C" void kernel_launch(void* const* d_in, const int* in_sizes, int n_in,
                              void* d_out, int out_size, void* d_ws, size_t ws_size,
                              hipStream_t stream){
  const float* x    =(const float*)d_in[0];
  const float* gn1w =(const float*)d_in[1];
  const float* gn1b =(const float*)d_in[2];
  const float* aw1  =(const float*)d_in[3];
  const float* ab1  =(const float*)d_in[4];
  const float* aw2  =(const float*)d_in[5];
  const float* ab2  =(const float*)d_in[6];
  const float* gn2w =(const float*)d_in[7];
  const float* gn2b =(const float*)d_in[8];
  const float* few  =(const float*)d_in[9];
  const float* feb  =(const float*)d_in[10];
  const float* g1w  =(const float*)d_in[11];
  const float* g1b  =(const float*)d_in[12];
  const float* bn1g =(const float*)d_in[13];
  const float* bn1b =(const float*)d_in[14];
  const float* bn1m =(const float*)d_in[15];
  const float* bn1v =(const float*)d_in[16];
  const float* cw1  =(const float*)d_in[17];
  const float* cb1  =(const float*)d_in[18];
  const float* cw2  =(const float*)d_in[19];
  const float* cb2  =(const float*)d_in[20];
  const float* g2w  =(const float*)d_in[21];
  const float* g2b  =(const float*)d_in[22];
  const float* bn2g =(const float*)d_in[23];
  const float* bn2b =(const float*)d_in[24];
  const float* bn2m =(const float*)d_in[25];
  const float* bn2v =(const float*)d_in[26];
  const float* g3w  =(const float*)d_in[27];
  const float* g3b  =(const float*)d_in[28];
  const float* shw  =(const float*)d_in[29];
  const float* shb  =(const float*)d_in[30];
  const float* exw  =(const float*)d_in[31];
  const float* exb  =(const float*)d_in[32];

  float* out=(float*)d_out;
  float* ws=(float*)d_ws;

  // workspace layout (float offsets)
  float*  part1 = ws;                         // 1024
  float*  part2 = ws+1024;                    // 1024
  float2* sb1   = (float2*)(ws+2048);         // 512 float2
  float2* sb2   = (float2*)(ws+3072);         // 512 float2
  float2* act   = (float2*)(ws+4096);         // 48 float2
  float*  gfp   = ws+4224;                    // 512
  float*  Xm2   = ws+8192;                    // 1048576
  float*  S2    = ws+1056768;                 // 1048576
  unsigned short* Tbl  = (unsigned short*)(ws+2105344);  // 61440 shorts
  unsigned short* wall = (unsigned short*)(ws+2136064);  // 73728 shorts
  float*          ball = ws+2172928;                     // 1152
  unsigned short* wfe  = (unsigned short*)(ws+2174080);  // 4096 shorts
  unsigned short* feats= (unsigned short*)(ws+2176128);  // 18874368 shorts (~37.7MB)
  unsigned short* h2b  = (unsigned short*)(ws+11613312); // 18874368 shorts (~37.7MB)
  const unsigned short* TBf1 = Tbl;
  const unsigned short* TBf2 = Tbl+12288;
  const unsigned short* TAi  = Tbl+36864;
  const unsigned short* TBi  = Tbl+49152;

  prep<<<64,256,0,stream>>>(shw, exw, shb, exb, few, Tbl, wall, ball, wfe, gfp);
  // AFNO on raw x (gn1 via linearity), emits gn1 stats
  fwd_dft <<<512,256,0,stream>>>(x, TBf1, TBf2, Xm2, part1);
  gn_finalize<<<1,64,0,stream>>>(part1, gn1w, gn1b, sb1);
  mode_mlp<<<256,256,0,stream>>>(Xm2, sb1, aw1, ab1, aw2, ab2, S2);
  inv_dft <<<512,256,0,stream>>>(S2, TAi, TBi, x, sb1, h2b, part2); // h2 -> bf16 workspace
  gn_finalize<<<1,64,0,stream>>>(part2, gn2w, gn2b, sb2);
  // gating means + feats materialization (bf16 in/out)
  gf_k<<<2304,256,0,stream>>>(h2b, sb2, wfe, feb, gfp, feats);
  gating <<<1,128,0,stream>>>(gfp, g1w,g1b, bn1g,bn1b,bn1m,bn1v,
                              cw1,cb1,cw2,cb2, g2w,g2b, bn2g,bn2b,bn2m,bn2v,
                              g3w,g3b, act);
  // experts: 1-wave blocks, zero barriers, pure full-line stores
  final_k<<<9216,64,0,stream>>>(feats, h2b, wall, ball, act, out);
}

// Round 18
// 199.783 us; speedup vs baseline: 1.1375x; 1.0138x over previous
//
#include <hip/hip_runtime.h>
#include <math.h>

// Problem constants: B=8, C=64, H=W=192, HW=36864, MODES=32, NB=4, BS=16, E=16
#define TPI 6.283185307179586f

typedef __attribute__((ext_vector_type(8))) short bf8v;   // 8 bf16 (4 VGPRs)
typedef __attribute__((ext_vector_type(4))) float f4v;    // 4 fp32 acc

#define MFMA(a,b,c) __builtin_amdgcn_mfma_f32_16x16x32_bf16((a),(b),(c),0,0,0)

__device__ __forceinline__ float gelu_f(float v){          // exact (erf)
  return 0.5f*v*(1.0f+erff(v*0.7071067811865475f));
}
// tanh-form gelu via fast exp + fast rcp (no IEEE div): err ~5e-4 abs
__device__ __forceinline__ float gelu_fast(float x){
  float x2=x*x;
  float inner=fmaf(0.044715f*x2, x, x);
  float e=__expf(1.5957691216057308f*inner);   // exp(2*0.7978845608*inner)
  float r=__builtin_amdgcn_rcpf(1.0f+e);
  return fmaf(-x, r, x);                        // x*(1-r)
}
// sigmoid-form gelu: x*sigmoid(1.702x). err <= ~0.0203 abs
__device__ __forceinline__ float gelu_sig(float x){
  float e=__expf(-1.702f*x);
  return x*__builtin_amdgcn_rcpf(1.0f+e);
}
__device__ __forceinline__ unsigned short f2b(float f){   // f32 -> bf16 (RNE)
  union{float f; unsigned u;} v; v.f=f;
  unsigned r=v.u + 0x7FFFu + ((v.u>>16)&1u);
  return (unsigned short)(r>>16);
}
__device__ __forceinline__ float b2f(unsigned short h){
  union{unsigned u; float f;} v; v.u=((unsigned)h)<<16; return v.f;
}

// ---------------- prep: twiddle tables + bf16 weights + zero gfp -----------
__global__ __launch_bounds__(256) void prep(const float* __restrict__ shw, const float* __restrict__ exw,
    const float* __restrict__ shb, const float* __restrict__ exb, const float* __restrict__ few,
    unsigned short* __restrict__ T, unsigned short* __restrict__ wall, float* __restrict__ ball,
    unsigned short* __restrict__ wfe, float* __restrict__ gfp){
  const float a = TPI/192.0f;
  int stride=gridDim.x*256;
  for(int i=blockIdx.x*256+threadIdx.x; i<61440; i+=stride){
    float v;
    if(i<12288){
      int n1=i/192, w=i%192; int kw=n1>>1, c=n1&1;
      int m=(kw*w)%192; float cs,sn; sincosf((float)m*a,&sn,&cs);
      v = c ? -sn : cs;
    } else if(i<36864){
      int j=i-12288; int n1=j/384, k1=j%384; int kh=n1>>1, d=n1&1; int h=k1>>1, c=k1&1;
      int m=(kh*h)%192; float cs,sn; sincosf((float)m*a,&sn,&cs);
      float e = d ? (c ? cs : -sn) : (c ? sn : cs);
      v = e*(1.0f/192.0f);
    } else if(i<49152){
      int j=i-36864; int h=j/64, k1=j%64; int kh=k1>>1, c=k1&1;
      int m=(h*kh)%192; float cs,sn; sincosf((float)m*a,&sn,&cs);
      v = c ? sn : cs;
    } else {
      int j=i-49152; int w=j/64, k1=j%64; int kw=k1>>1, d=k1&1;
      float f = kw ? (2.0f/192.0f) : (1.0f/192.0f);
      int m=(w*kw)%192; float cs,sn; sincosf((float)m*a,&sn,&cs);
      v = d ? -f*sn : f*cs;
    }
    T[i]=f2b(v);
  }
  for(int i=blockIdx.x*256+threadIdx.x;i<73728;i+=stride) wall[i]=f2b(i<8192?shw[i]:exw[i-8192]);
  for(int i=blockIdx.x*256+threadIdx.x;i<1152;i+=stride)  ball[i]=(i<128)?shb[i]:exb[i-128];
  for(int i=blockIdx.x*256+threadIdx.x;i<4096;i+=stride)  wfe[i]=f2b(few[i]);
  for(int i=blockIdx.x*256+threadIdx.x;i<512;i+=stride)   gfp[i]=0.f;
}

__global__ void gn_finalize(const float* __restrict__ part, const float* __restrict__ gw,
                            const float* __restrict__ gb, float2* __restrict__ sb){
  int g=threadIdx.x; if(g>=64) return;
  float S=0,SS=0;
  for(int j=0;j<8;j++){ S+=part[(g*8+j)*2]; SS+=part[(g*8+j)*2+1]; }
  const float inv=1.0f/294912.0f;
  float mean=S*inv, var=SS*inv-mean*mean;
  float rstd=rsqrtf(var+1e-5f);
  int b=g>>3, gg=g&7;
  for(int k=0;k<8;k++){
    int c=gg*8+k;
    float sc=rstd*gw[c];
    sb[b*64+c]=make_float2(sc, gb[c]-mean*sc);
  }
}

// ---------------- fwd DFT on RAW x (gn1 folded out via linearity) ---------
__global__ __launch_bounds__(256) void fwd_dft(const float* __restrict__ x,
      const unsigned short* __restrict__ TBf1, const unsigned short* __restrict__ TBf2,
      float* __restrict__ Xm2, float* __restrict__ part1){
  __shared__ __align__(16) unsigned short ldsA[64*200];  // Bt1 [64][200]; later tL [32][392]
  __shared__ __align__(16) float sX[2048];
  __shared__ float red[8];
  int t=threadIdx.x, bc=blockIdx.x;
  int wave=t>>6, l=t&63, lr=l&15, lg=l>>4;
  const float* xch = x + (size_t)bc*36864;
  for(int i=t;i<1536;i+=256){
    int row=i/24, chunk=i%24;
    *(uint4*)&ldsA[row*200 + chunk*8] = *(const uint4*)(TBf1 + row*192 + chunk*8);
  }
  __syncthreads();
  float s_=0.f, ss_=0.f;
  // ---- stage 1 ----
  f4v acc1[3][4];
  for(int mt=0;mt<3;mt++){
    int m0=(wave+mt*4)*16;
    const float* xrow = xch + (m0+lr)*192 + lg*8;
    bf8v af[6];
    #pragma unroll
    for(int ks=0;ks<6;ks++){
      float4 u0=*(const float4*)(xrow+ks*32);
      float4 u1=*(const float4*)(xrow+ks*32+4);
      s_ += u0.x+u0.y+u0.z+u0.w+u1.x+u1.y+u1.z+u1.w;
      ss_+= u0.x*u0.x+u0.y*u0.y+u0.z*u0.z+u0.w*u0.w
           +u1.x*u1.x+u1.y*u1.y+u1.z*u1.z+u1.w*u1.w;
      bf8v a;
      a[0]=(short)f2b(u0.x); a[1]=(short)f2b(u0.y); a[2]=(short)f2b(u0.z); a[3]=(short)f2b(u0.w);
      a[4]=(short)f2b(u1.x); a[5]=(short)f2b(u1.y); a[6]=(short)f2b(u1.z); a[7]=(short)f2b(u1.w);
      af[ks]=a;
    }
    #pragma unroll
    for(int nt=0;nt<4;nt++){
      f4v acc={0.f,0.f,0.f,0.f};
      #pragma unroll
      for(int ks=0;ks<6;ks++){
        bf8v b=*(const bf8v*)&ldsA[(nt*16+lr)*200 + ks*32 + lg*8];
        acc=MFMA(af[ks],b,acc);
      }
      acc1[mt][nt]=acc;
    }
  }
  __syncthreads();            // reuse ldsA as tL [32][392]
  for(int mt=0;mt<3;mt++){
    int m0=(wave+mt*4)*16;
    #pragma unroll
    for(int nt=0;nt<4;nt++){
      int n1=nt*16+lr; int kw=n1>>1, c=n1&1;
      #pragma unroll
      for(int reg=0;reg<4;reg++){
        int h=m0+4*lg+reg;
        ldsA[kw*392 + 2*h + c]=f2b(acc1[mt][nt][reg]);
      }
    }
  }
  __syncthreads();
  // ---- stage 2 ----
  for(int pp=0;pp<2;pp++){
    int p=wave+pp*4;
    int m0=(p>>2)*16, n0=(p&3)*16;
    f4v acc={0.f,0.f,0.f,0.f};
    #pragma unroll
    for(int ks=0;ks<12;ks++){
      bf8v a=*(const bf8v*)&ldsA[(m0+lr)*392 + ks*32 + lg*8];
      bf8v b=*(const bf8v*)(TBf2 + (n0+lr)*384 + ks*32 + lg*8);
      acc=MFMA(a,b,acc);
    }
    int n1=n0+lr; int kh=n1>>1, d=n1&1;
    #pragma unroll
    for(int reg=0;reg<4;reg++){
      int kw=m0+4*lg+reg;
      sX[(kh*32+kw)*2 + d]=acc[reg];
    }
  }
  __syncthreads();
  float* dst=Xm2+(size_t)bc*2048;
  for(int i=t;i<512;i+=256) *(float4*)(dst+i*4)=*(const float4*)(sX+i*4);
  // ---- gn1 stats ----
  #pragma unroll
  for(int o=32;o>0;o>>=1){ s_+=__shfl_down(s_,o); ss_+=__shfl_down(ss_,o); }
  if(l==0){ red[wave]=s_; red[4+wave]=ss_; }
  __syncthreads();
  if(t==0){
    part1[bc*2]  =red[0]+red[1]+red[2]+red[3];
    part1[bc*2+1]=red[4]+red[5]+red[6]+red[7];
  }
}

// ---------------- block-diagonal complex 2-layer MLP on modes -------------
__global__ __launch_bounds__(256) void mode_mlp(const float* __restrict__ Xm2, const float2* __restrict__ sb1,
    const float* __restrict__ w1, const float* __restrict__ b1,
    const float* __restrict__ w2, const float* __restrict__ b2,
    float* __restrict__ S2){
  __shared__ float w10[1024], w11[1024], w20[1024], w21[1024];
  __shared__ float b10[64], b11[64], b20[64], b21[64];
  __shared__ float2 sbl[64];
  __shared__ float xr[32][64], xi[32][64];
  __shared__ float o1r[32][64], o1i[32][64];
  int t=threadIdx.x;
  int b=blockIdx.x>>5, kh=blockIdx.x&31;
  for(int i=t;i<1024;i+=256){ w10[i]=w1[i]; w11[i]=w1[1024+i]; w20[i]=w2[i]; w21[i]=w2[1024+i]; }
  if(t<64){ b10[t]=b1[t]; b11[t]=b1[64+t]; b20[t]=b2[t]; b21[t]=b2[64+t]; sbl[t]=sb1[b*64+t]; }
  __syncthreads();
  for(int q=0;q<16;q++){
    int idx=q*256+t; int c=idx>>6, jj=idx&63;
    float2 s=sbl[c];
    float v=Xm2[((size_t)(b*64+c))*2048 + kh*64 + jj]*s.x;
    if(kh==0 && jj==0) v += 192.0f*s.y;
    if(jj&1) xi[jj>>1][c]=v; else xr[jj>>1][c]=v;
  }
  __syncthreads();
  int tl=t&63, n=tl>>4, o=tl&15, wb=n*256+o;
  #pragma unroll
  for(int it=0;it<8;it++){
    int kw=(t>>6)+it*4;
    float a_r=b10[tl], a_i=b11[tl];
    #pragma unroll
    for(int i=0;i<16;i++){
      float rr=xr[kw][n*16+i], im=xi[kw][n*16+i];
      float W0=w10[wb+i*16], W1=w11[wb+i*16];
      a_r=fmaf(rr,W0,fmaf(-im,W1,a_r));
      a_i=fmaf(im,W0,fmaf( rr,W1,a_i));
    }
    o1r[kw][tl]=gelu_f(a_r); o1i[kw][tl]=gelu_f(a_i);
  }
  __syncthreads();
  #pragma unroll
  for(int it=0;it<8;it++){
    int kw=(t>>6)+it*4;
    float c_r=b20[tl], c_i=b21[tl];
    #pragma unroll
    for(int i=0;i<16;i++){
      float rr=o1r[kw][n*16+i], im=o1i[kw][n*16+i];
      float W0=w20[wb+i*16], W1=w21[wb+i*16];
      c_r=fmaf(rr,W0,fmaf(-im,W1,c_r));
      c_i=fmaf(im,W0,fmaf( rr,W1,c_i));
    }
    xr[kw][tl]=c_r; xi[kw][tl]=c_i;
  }
  __syncthreads();
  for(int q=0;q<16;q++){
    int idx=q*256+t; int c=idx>>6, jj=idx&63;
    float v = (jj&1) ? xi[jj>>1][c] : xr[jj>>1][c];
    S2[((size_t)(b*64+c))*2048 + kh*64 + jj]=v;
  }
}

// ---------------- inverse DFT + residuals + gn2 stats (h2 -> bf16) --------
__global__ __launch_bounds__(256) void inv_dft(const float* __restrict__ S2,
      const unsigned short* __restrict__ TAi, const unsigned short* __restrict__ TBi,
      const float* __restrict__ x, const float2* __restrict__ sb,
      unsigned short* __restrict__ h2b, float* __restrict__ part2){
  __shared__ __align__(16) unsigned short Bs[64*72];
  __shared__ __align__(16) unsigned short GL[192*72];
  __shared__ float red[8];
  int t=threadIdx.x, bc=blockIdx.x;
  int wave=t>>6, l=t&63, lr=l&15, lg=l>>4;
  const float* sp=S2+(size_t)bc*2048;
  for(int i=t;i<1024;i+=256){
    int kh=i>>5, kw=i&31;
    float Sr=sp[(kh*32+kw)*2], Si=sp[(kh*32+kw)*2+1];
    unsigned short br=f2b(Sr), bi_=f2b(Si), nbi=f2b(-Si);
    Bs[(2*kw+0)*72 + 2*kh+0]=br;
    Bs[(2*kw+0)*72 + 2*kh+1]=nbi;
    Bs[(2*kw+1)*72 + 2*kh+0]=bi_;
    Bs[(2*kw+1)*72 + 2*kh+1]=br;
  }
  __syncthreads();
  for(int mt=0;mt<3;mt++){
    int m0=(wave+mt*4)*16;
    bf8v a0=*(const bf8v*)(TAi + (m0+lr)*64 + lg*8);
    bf8v a1=*(const bf8v*)(TAi + (m0+lr)*64 + 32 + lg*8);
    #pragma unroll
    for(int nt=0;nt<4;nt++){
      f4v acc={0.f,0.f,0.f,0.f};
      bf8v b0=*(const bf8v*)&Bs[(nt*16+lr)*72 + lg*8];
      bf8v b1=*(const bf8v*)&Bs[(nt*16+lr)*72 + 32 + lg*8];
      acc=MFMA(a0,b0,acc); acc=MFMA(a1,b1,acc);
      #pragma unroll
      for(int reg=0;reg<4;reg++)
        GL[(m0+4*lg+reg)*72 + nt*16+lr]=f2b(acc[reg]);
    }
  }
  __syncthreads();
  float2 sv=sb[bc];
  float cA=sv.x+1.0f, cB=sv.y;
  asm volatile("" : "+v"(cA), "+v"(cB));   // pin to VGPR (constant-bus fix)
  const float* xch=x+(size_t)bc*36864;
  unsigned short* och=h2b+(size_t)bc*36864;
  float s_=0.f, ss_=0.f;
  for(int mt=0;mt<3;mt++){
    int m0=(wave+mt*4)*16;
    bf8v a0=*(const bf8v*)&GL[(m0+lr)*72 + lg*8];
    bf8v a1=*(const bf8v*)&GL[(m0+lr)*72 + 32 + lg*8];
    for(int nt=0;nt<12;nt++){
      int n0=nt*16;
      f4v acc={0.f,0.f,0.f,0.f};
      bf8v b0=*(const bf8v*)(TBi + (n0+lr)*64 + lg*8);
      bf8v b1=*(const bf8v*)(TBi + (n0+lr)*64 + 32 + lg*8);
      acc=MFMA(a0,b0,acc); acc=MFMA(a1,b1,acc);
      int w=n0+lr;
      #pragma unroll
      for(int reg=0;reg<4;reg++){
        int h=m0+4*lg+reg;
        int ga=h*192+w;
        float xv=xch[ga];
        float val=acc[reg]+fmaf(cA,xv,cB);
        och[ga]=f2b(val);
        s_+=val; ss_+=val*val;
      }
    }
  }
  #pragma unroll
  for(int o=32;o>0;o>>=1){ s_+=__shfl_down(s_,o); ss_+=__shfl_down(ss_,o); }
  if(l==0){ red[wave]=s_; red[4+wave]=ss_; }
  __syncthreads();
  if(t==0){
    part2[bc*2]  =red[0]+red[1]+red[2]+red[3];
    part2[bc*2+1]=red[4]+red[5]+red[6]+red[7];
  }
}

// ---------------- gf_k: gating means + feats materialization (bf16 in) ----
__global__ __launch_bounds__(256,4) void gf_k(const unsigned short* __restrict__ h2b, const float2* __restrict__ sb,
    const unsigned short* __restrict__ wfe, const float* __restrict__ feb,
    float* __restrict__ gfp, unsigned short* __restrict__ feats){
  __shared__ __align__(16) unsigned short A[128*72];
  __shared__ float sgf[64];
  int t=threadIdx.x;
  int blk=blockIdx.x, b=blk/288, tile=blk-b*288, hw0=tile*128;
  if(t<64) sgf[t]=0.f;
  // batched staging loads (4 outstanding uint4 = 8 bf16 each)
  uint4 v[4];
  #pragma unroll
  for(int k=0;k<4;k++){
    int i=t+k*256; int c=i>>4, o=i&15;
    v[k]=*(const uint4*)&h2b[(size_t)(b*64+c)*36864 + hw0 + o*8];
  }
  #pragma unroll
  for(int k=0;k<4;k++){
    int i=t+k*256; int c=i>>4, o=i&15;
    float2 s=sb[b*64+c];
    int sw=((o>>1)&3)<<3, cc=c^sw;
    const unsigned short* pv=(const unsigned short*)&v[k];
    #pragma unroll
    for(int r=0;r<8;r++)
      A[(o*8+r)*72+cc]=f2b(fmaf(b2f(pv[r]),s.x,s.y));
  }
  __syncthreads();
  int wave=t>>6, l=t&63, lr=l&15, lg=l>>4;
  int pxb=wave*32;
  bf8v af[2][2];
  #pragma unroll
  for(int fm=0;fm<2;fm++){
    int row=pxb+fm*16+lr, sw=((row>>4)&3)<<3;
    #pragma unroll
    for(int ks=0;ks<2;ks++) af[fm][ks]=*(const bf8v*)&A[row*72+((ks*32+lg*8)^sw)];
  }
  float gsum[4]={0.f,0.f,0.f,0.f};
  #pragma unroll
  for(int fn=0;fn<4;fn++){
    bf8v b0=*(const bf8v*)(wfe+(fn*16+lr)*64+lg*8);
    bf8v b1=*(const bf8v*)(wfe+(fn*16+lr)*64+32+lg*8);
    float bs=feb[fn*16+lr];
    #pragma unroll
    for(int fm=0;fm<2;fm++){
      f4v acc={0.f,0.f,0.f,0.f};
      acc=MFMA(af[fm][0],b0,acc);
      acc=MFMA(af[fm][1],b1,acc);
      int swm=(((pxb+fm*16)>>4)&3)<<3;
      int cc=(fn*16+lr)^swm;
      #pragma unroll
      for(int r=0;r<4;r++){
        float g=gelu_fast(acc[r]+bs);
        gsum[fn]+=g;
        A[(pxb+fm*16+4*lg+r)*72+cc]=f2b(g);   // wave-private rows
      }
    }
  }
  #pragma unroll
  for(int fn=0;fn<4;fn++){
    float v2=gsum[fn];
    v2+=__shfl_xor(v2,16); v2+=__shfl_xor(v2,32);
    if(lg==0) atomicAdd(&sgf[fn*16+lr], v2);
  }
  __syncthreads();
  if(t<64) atomicAdd(&gfp[b*64+t], sgf[t]);
  // store feats tile bf16 (coalesced: 128B contiguous per 8 threads)
  #pragma unroll
  for(int k=0;k<4;k++){
    int i=t+k*256; int px=i>>3, c0=(i&7)*8, sw=((px>>4)&3)<<3;
    *(uint4*)&feats[(size_t)(b*36864+hw0+px)*64+c0] = *(const uint4*)&A[px*72+(c0^sw)];
  }
}

// ---------------- gating MLP + top-4 softmax -> active-term list ----------
__global__ __launch_bounds__(128) void gating(const float* __restrict__ gfp,
  const float* __restrict__ g1w, const float* __restrict__ g1b,
  const float* __restrict__ bn1g, const float* __restrict__ bn1b, const float* __restrict__ bn1m, const float* __restrict__ bn1v,
  const float* __restrict__ cw1, const float* __restrict__ cb1, const float* __restrict__ cw2, const float* __restrict__ cb2,
  const float* __restrict__ g2w, const float* __restrict__ g2b,
  const float* __restrict__ bn2g, const float* __restrict__ bn2b, const float* __restrict__ bn2m, const float* __restrict__ bn2v,
  const float* __restrict__ g3w, const float* __restrict__ g3b, float2* __restrict__ act){
  __shared__ float gf[8][64];
  __shared__ float h1[8][128];
  __shared__ float a1[8][8];
  __shared__ float h2g[8][64];
  __shared__ float sc[8][16];
  int t=threadIdx.x;
  for(int i=t;i<512;i+=128) gf[i>>6][i&63]=gfp[i]*(1.0f/36864.0f);
  __syncthreads();
  for(int i=t;i<1024;i+=128){
    int b=i>>7, j=i&127;
    float s=g1b[j];
    for(int c=0;c<64;c++) s=fmaf(gf[b][c], g1w[j*64+c], s);
    s=(s-bn1m[j])*rsqrtf(bn1v[j]+1e-5f)*bn1g[j]+bn1b[j];
    h1[b][j]=gelu_f(s);
  }
  __syncthreads();
  if(t<64){
    int b=t>>3, k=t&7; float s=cb1[k];
    for(int j=0;j<128;j++) s=fmaf(h1[b][j], cw1[k*128+j], s);
    a1[b][k]=gelu_f(s);
  }
  __syncthreads();
  for(int i=t;i<1024;i+=128){
    int b=i>>7, j=i&127;
    float s=cb2[j];
    for(int k=0;k<8;k++) s=fmaf(a1[b][k], cw2[j*8+k], s);
    h1[b][j]=h1[b][j]/(1.0f+expf(-2.0f*s));
  }
  __syncthreads();
  for(int i=t;i<512;i+=128){
    int b=i>>6, j=i&63;
    float s=g2b[j];
    for(int k=0;k<128;k++) s=fmaf(h1[b][k], g2w[j*128+k], s);
    s=(s-bn2m[j])*rsqrtf(bn2v[j]+1e-5f)*bn2g[j]+bn2b[j];
    h2g[b][j]=gelu_f(s);
  }
  __syncthreads();
  {
    int b=t>>4, e=t&15;
    float s=g3b[e];
    for(int c=0;c<64;c++) s=fmaf(h2g[b][c], g3w[e*64+c], s);
    sc[b][e]=s;
  }
  __syncthreads();
  if(t<8){
    int b=t;
    float v[16];
    for(int e=0;e<16;e++) v[e]=sc[b][e];
    float vals[4]; int idx[4];
    for(int k=0;k<4;k++){
      float best=-1e30f; int bi=0;
      for(int e=0;e<16;e++) if(v[e]>best){best=v[e];bi=e;}
      vals[k]=best; idx[k]=bi; v[bi]=-1e30f;
    }
    float m=vals[0], ssum=0.f, w[4];
    for(int k=0;k<4;k++){ w[k]=expf((vals[k]-m)*0.5f); ssum+=w[k]; }
    act[b*6+0]=make_float2(0.5f, __int_as_float(0));
    act[b*6+1]=make_float2(0.5f, __int_as_float(1));
    for(int k=0;k<4;k++) act[b*6+2+k]=make_float2(w[k]/ssum, __int_as_float(2+idx[k]));
  }
}

// ---------------- experts: 1-wave blocks + deep register preload ----------
// All 24 weight fragments + biases of a half preloaded into regs BEFORE any
// MFMA (24-deep load pipeline per wave). No waves-per-EU floor: let the
// compiler take ~160 VGPRs. Zero barriers; full-line pure stores.
__global__ __launch_bounds__(64) void final_k(const unsigned short* __restrict__ feats,
  const unsigned short* __restrict__ h2b,
  const unsigned short* __restrict__ wall, const float* __restrict__ ball,
  const float2* __restrict__ act, float* __restrict__ out){
  __shared__ __align__(16) float Fo[32*36];   // [ocl][px], 4608 B
  int l=threadIdx.x, lr=l&15, lg=l>>4;
  int blk=blockIdx.x, b=blk/1152, rem=blk-b*1152, hw0=rem*32;
  // preload active-term list (uniform per b)
  float gv[6]; int tv[6];
  #pragma unroll
  for(int j=0;j<6;j++){
    float2 aw=act[b*6+j];
    gv[j]=aw.x; tv[j]=__float_as_int(aw.y);
  }
  const unsigned short* fbase = feats + (size_t)(b*36864+hw0)*64;
  bf8v af2[2][2];
  #pragma unroll
  for(int fm=0;fm<2;fm++){
    int row=fm*16+lr;
    #pragma unroll
    for(int ks=0;ks<2;ks++)
      af2[fm][ks]=*(const bf8v*)(fbase + (size_t)row*64 + ks*32 + lg*8);
  }
  // ---- per oc-half: preload ALL weights -> 6 terms -> repack -> store ----
  #pragma unroll
  for(int half=0;half<2;half++){
    // 24-deep weight load burst + biases (all independent)
    bf8v wv[6][2][2]; float bsv[6][2];
    #pragma unroll
    for(int j=0;j<6;j++){
      const unsigned short* wp=wall+tv[j]*4096;
      #pragma unroll
      for(int fn2=0;fn2<2;fn2++){
        int fn=half*2+fn2;
        wv[j][fn2][0]=*(const bf8v*)(wp+(fn*16+lr)*64+lg*8);
        wv[j][fn2][1]=*(const bf8v*)(wp+(fn*16+lr)*64+32+lg*8);
        bsv[j][fn2]=ball[tv[j]*64+fn*16+lr];
      }
    }
    float oa[2][2][4]={};       // [fm][fn2][r]
    #pragma unroll
    for(int j=0;j<6;j++){
      float g=gv[j];
      #pragma unroll
      for(int fn2=0;fn2<2;fn2++){
        float bs=bsv[j][fn2];
        #pragma unroll
        for(int fm=0;fm<2;fm++){
          f4v acc={0.f,0.f,0.f,0.f};
          acc=MFMA(af2[fm][0],wv[j][fn2][0],acc);
          acc=MFMA(af2[fm][1],wv[j][fn2][1],acc);
          #pragma unroll
          for(int r=0;r<4;r++)
            oa[fm][fn2][r]=fmaf(g, gelu_sig(acc[r]+bs), oa[fm][fn2][r]);
        }
      }
    }
    // wave-private repack (no barrier: same-wave LDS is program-ordered)
    #pragma unroll
    for(int fm=0;fm<2;fm++)
      #pragma unroll
      for(int fn2=0;fn2<2;fn2++){
        int ocl=fn2*16+lr;
        *(float4*)&Fo[ocl*36 + fm*16 + 4*lg] =
            make_float4(oa[fm][fn2][0],oa[fm][fn2][1],oa[fm][fn2][2],oa[fm][fn2][3]);
      }
    // coalesced pure stores: 8 threads x float4 = 128B contiguous per oc row
    #pragma unroll
    for(int k=0;k<4;k++){
      int idx=l+64*k;             // 0..255
      int ocl=idx>>3, q=idx&7;
      int oc=half*32+ocl;
      size_t base=(size_t)(b*64+oc)*36864 + hw0 + q*4;
      ushort4 hv=*(const ushort4*)&h2b[base];
      float4 ov=*(const float4*)&Fo[ocl*36+q*4];
      *(float4*)&out[base]=make_float4(ov.x+b2f(hv.x),ov.y+b2f(hv.y),
                                       ov.z+b2f(hv.z),ov.w+b2f(hv.w));
    }
  }
}

extern "C" void kernel_launch(void* const* d_in, const int* in_sizes, int n_in,
                              void* d_out, int out_size, void* d_ws, size_t ws_size,
                              hipStream_t stream){
  const float* x    =(const float*)d_in[0];
  const float* gn1w =(const float*)d_in[1];
  const float* gn1b =(const float*)d_in[2];
  const float* aw1  =(const float*)d_in[3];
  const float* ab1  =(const float*)d_in[4];
  const float* aw2  =(const float*)d_in[5];
  const float* ab2  =(const float*)d_in[6];
  const float* gn2w =(const float*)d_in[7];
  const float* gn2b =(const float*)d_in[8];
  const float* few  =(const float*)d_in[9];
  const float* feb  =(const float*)d_in[10];
  const float* g1w  =(const float*)d_in[11];
  const float* g1b  =(const float*)d_in[12];
  const float* bn1g =(const float*)d_in[13];
  const float* bn1b =(const float*)d_in[14];
  const float* bn1m =(const float*)d_in[15];
  const float* bn1v =(const float*)d_in[16];
  const float* cw1  =(const float*)d_in[17];
  const float* cb1  =(const float*)d_in[18];
  const float* cw2  =(const float*)d_in[19];
  const float* cb2  =(const float*)d_in[20];
  const float* g2w  =(const float*)d_in[21];
  const float* g2b  =(const float*)d_in[22];
  const float* bn2g =(const float*)d_in[23];
  const float* bn2b =(const float*)d_in[24];
  const float* bn2m =(const float*)d_in[25];
  const float* bn2v =(const float*)d_in[26];
  const float* g3w  =(const float*)d_in[27];
  const float* g3b  =(const float*)d_in[28];
  const float* shw  =(const float*)d_in[29];
  const float* shb  =(const float*)d_in[30];
  const float* exw  =(const float*)d_in[31];
  const float* exb  =(const float*)d_in[32];

  float* out=(float*)d_out;
  float* ws=(float*)d_ws;

  // workspace layout (float offsets)
  float*  part1 = ws;                         // 1024
  float*  part2 = ws+1024;                    // 1024
  float2* sb1   = (float2*)(ws+2048);         // 512 float2
  float2* sb2   = (float2*)(ws+3072);         // 512 float2
  float2* act   = (float2*)(ws+4096);         // 48 float2
  float*  gfp   = ws+4224;                    // 512
  float*  Xm2   = ws+8192;                    // 1048576
  float*  S2    = ws+1056768;                 // 1048576
  unsigned short* Tbl  = (unsigned short*)(ws+2105344);  // 61440 shorts
  unsigned short* wall = (unsigned short*)(ws+2136064);  // 73728 shorts
  float*          ball = ws+2172928;                     // 1152
  unsigned short* wfe  = (unsigned short*)(ws+2174080);  // 4096 shorts
  unsigned short* feats= (unsigned short*)(ws+2176128);  // 18874368 shorts (~37.7MB)
  unsigned short* h2b  = (unsigned short*)(ws+11613312); // 18874368 shorts (~37.7MB)
  const unsigned short* TBf1 = Tbl;
  const unsigned short* TBf2 = Tbl+12288;
  const unsigned short* TAi  = Tbl+36864;
  const unsigned short* TBi  = Tbl+49152;

  prep<<<64,256,0,stream>>>(shw, exw, shb, exb, few, Tbl, wall, ball, wfe, gfp);
  // AFNO on raw x (gn1 via linearity), emits gn1 stats
  fwd_dft <<<512,256,0,stream>>>(x, TBf1, TBf2, Xm2, part1);
  gn_finalize<<<1,64,0,stream>>>(part1, gn1w, gn1b, sb1);
  mode_mlp<<<256,256,0,stream>>>(Xm2, sb1, aw1, ab1, aw2, ab2, S2);
  inv_dft <<<512,256,0,stream>>>(S2, TAi, TBi, x, sb1, h2b, part2); // h2 -> bf16 workspace
  gn_finalize<<<1,64,0,stream>>>(part2, gn2w, gn2b, sb2);
  // gating means + feats materialization (bf16 in/out)
  gf_k<<<2304,256,0,stream>>>(h2b, sb2, wfe, feb, gfp, feats);
  gating <<<1,128,0,stream>>>(gfp, g1w,g1b, bn1g,bn1b,bn1m,bn1v,
                              cw1,cb1,cw2,cb2, g2w,g2b, bn2g,bn2b,bn2m,bn2v,
                              g3w,g3b, act);
  // experts: 1-wave blocks, deep register preload, pure full-line stores
  final_k<<<9216,64,0,stream>>>(feats, h2b, wall, ball, act, out);
}